// Round 8
// baseline (248.625 us; speedup 1.0000x reference)
//
#include <hip/hip_runtime.h>
#include <cmath>

#define B_   2
#define L_   2048
#define DM_  512
#define DI_  1024
#define DS_  16
#define DTR_ 32
#define M_   (B_*L_)   // 4096
#define NC_  64        // chunks
#define CL_  32        // chunk length (NC_*CL_ == L_)
#define KS_  8         // GEMM2 split-K factor
#define LOG2E_ 1.44269504088896340736f
#define LN2_   0.69314718055994530942f

typedef __attribute__((ext_vector_type(8))) short short8;   // 8 bf16 = 4 VGPRs
typedef __attribute__((ext_vector_type(4))) float floatx4;  // MFMA acc

__device__ inline unsigned short f2bf(float f) {
  unsigned u = __float_as_uint(f);
  unsigned r = (u + 0x7fffu + ((u >> 16) & 1u)) >> 16;   // RNE
  return (unsigned short)r;
}
__device__ inline float bf2f(unsigned short u) {
  return __uint_as_float(((unsigned)u) << 16);
}
// fp16 pack/unpack (v_cvt_f16_f32 / v_cvt_f32_f16)
__device__ inline unsigned short f2h(float f) {
  _Float16 h = (_Float16)f;
  return *(unsigned short*)&h;
}
__device__ inline float h2f(unsigned short u) {
  _Float16 h = *(_Float16*)&u;
  return (float)h;
}
// raw v_exp_f32 (2^x) / v_log_f32 (log2 x) — libm exp2f/log1pf are slow multi-inst paths
__device__ inline float fexp2(float x) { return __builtin_amdgcn_exp2f(x); }
__device__ inline float flog2(float x) { return __builtin_amdgcn_logf(x); }

__device__ inline void gload_lds16(const unsigned short* g, unsigned short* l) {
  __builtin_amdgcn_global_load_lds(
      (const __attribute__((address_space(1))) void*)g,
      (__attribute__((address_space(3))) void*)l, 16, 0, 0);
}

// ---------------------------------------------------------------------------
// GEMM1 (bf16 MFMA, BOTH dirs fused in one block): xz_f = x.Win_f^T,
// xz_r = x.Win_r^T. One A-tile staged per K-step feeds TWO W-tiles ->
// 32 MFMA/wave per K-step vs 16, staging 24KB vs 2x16KB. Dual acc (128 VGPR).
// ---------------------------------------------------------------------------
__global__ __launch_bounds__(256, 2) void gemm1_mfma_k(
    const unsigned short* __restrict__ A,
    const unsigned short* __restrict__ Wf, const unsigned short* __restrict__ Wr,
    unsigned short* __restrict__ Cf, unsigned short* __restrict__ Cr,
    int N, int K)
{
  __shared__ unsigned short At[2][128 * 32];
  __shared__ unsigned short Wtf[2][128 * 32];
  __shared__ unsigned short Wtr[2][128 * 32];
  const int tid  = threadIdx.x;
  const int w    = tid >> 6;
  const int lane = tid & 63;
  const int wm   = w >> 1, wn = w & 1;
  const int row0 = blockIdx.y * 128, col0 = blockIdx.x * 128;
  const int lrow  = lane >> 2;
  const int lkoff = (lane & 3) * 8;
  const int fr = lane & 15;
  const int fq = (lane >> 4) * 8;

  floatx4 accf[4][4], accr[4][4];
#pragma unroll
  for (int i = 0; i < 4; ++i)
#pragma unroll
    for (int j = 0; j < 4; ++j)
#pragma unroll
      for (int r = 0; r < 4; ++r) { accf[i][j][r] = 0.f; accr[i][j][r] = 0.f; }

  auto stage = [&](int buf, int k0) {
#pragma unroll
    for (int j = 0; j < 2; ++j) {
      int r = w * 32 + j * 16;
      gload_lds16(A  + (size_t)(row0 + r + lrow) * K + k0 + lkoff, At[buf]  + r * 32);
      gload_lds16(Wf + (size_t)(col0 + r + lrow) * K + k0 + lkoff, Wtf[buf] + r * 32);
      gload_lds16(Wr + (size_t)(col0 + r + lrow) * K + k0 + lkoff, Wtr[buf] + r * 32);
    }
  };
  auto compute = [&](int buf) {
    short8 af[4], bff[4], bfr[4];
#pragma unroll
    for (int i = 0; i < 4; ++i) {
      af[i]  = *(const short8*)&At[buf][(64 * wm + 16 * i + fr) * 32 + fq];
      bff[i] = *(const short8*)&Wtf[buf][(64 * wn + 16 * i + fr) * 32 + fq];
      bfr[i] = *(const short8*)&Wtr[buf][(64 * wn + 16 * i + fr) * 32 + fq];
    }
#pragma unroll
    for (int i = 0; i < 4; ++i)
#pragma unroll
      for (int j = 0; j < 4; ++j) {
        accf[i][j] = __builtin_amdgcn_mfma_f32_16x16x32_bf16(af[i], bff[j], accf[i][j], 0, 0, 0);
        accr[i][j] = __builtin_amdgcn_mfma_f32_16x16x32_bf16(af[i], bfr[j], accr[i][j], 0, 0, 0);
      }
  };

  const int NT = K >> 5;
  stage(0, 0);
  __syncthreads();
  int cur = 0;
  for (int t = 0; t < NT - 1; ++t) {
    stage(cur ^ 1, (t + 1) << 5);
    compute(cur);
    __syncthreads();
    cur ^= 1;
  }
  compute(cur);

#pragma unroll
  for (int i = 0; i < 4; ++i) {
    int rg = row0 + 64 * wm + 16 * i + ((lane >> 4) << 2);
#pragma unroll
    for (int j = 0; j < 4; ++j) {
      int cg = col0 + 64 * wn + 16 * j + (lane & 15);
#pragma unroll
      for (int r = 0; r < 4; ++r) {
        Cf[(size_t)(rg + r) * N + cg] = f2bf(accf[i][j][r]);
        Cr[(size_t)(rg + r) * N + cg] = f2bf(accr[i][j][r]);
      }
    }
  }
}

// ---------------------------------------------------------------------------
// GEMM4 fused (bf16 MFMA): out = y_f . Wout_f^T + y_r . Wout_r^T  (fp32 out)
// 128x64 tile, 8 waves (512 thr, one 16-row band each): FLOP/staged-byte
// 42.7 vs 32 for the old 64x64 tile. BK=64 as two [.][32] k-half subtiles,
// single-barrier double-buffered pipeline. Per-output K-order identical to
// the 64x64 version -> bitwise-identical result.
// ---------------------------------------------------------------------------
__global__ __launch_bounds__(512, 2) void gemm4_fused_k(
    const unsigned short* __restrict__ ybf, const unsigned short* __restrict__ Woutbf,
    const unsigned short* __restrict__ ybr, const unsigned short* __restrict__ Woutbr,
    float* __restrict__ out)
{
  __shared__ unsigned short At[2][2][128 * 32];   // [buf][khalf] 8KB each
  __shared__ unsigned short Wt[2][2][64 * 32];    // [buf][khalf] 4KB each
  const int tid  = threadIdx.x;
  const int w    = tid >> 6;          // 0..7
  const int lane = tid & 63;
  const int col0 = blockIdx.x * 64;
  const int row0 = blockIdx.y * 128;
  const int lrow  = lane >> 2;
  const int lkoff = (lane & 3) * 8;
  const int fr = lane & 15;
  const int fq = (lane >> 4) * 8;

  floatx4 acc[4];
#pragma unroll
  for (int j = 0; j < 4; ++j)
#pragma unroll
    for (int r = 0; r < 4; ++r) acc[j][r] = 0.f;

  // t in [0,32): src = t>>4, k0 = (t&15)*64
  auto stage = [&](int buf, int t) {
    const unsigned short* A = (t & 16) ? ybr : ybf;
    const unsigned short* W = (t & 16) ? Woutbr : Woutbf;
    const int k0 = (t & 15) << 6;
    // A: 128 rows x 2 khalves; wave w stages rows [16w,16w+16) of each khalf
#pragma unroll
    for (int h = 0; h < 2; ++h) {
      gload_lds16(A + (size_t)(row0 + 16 * w + lrow) * DI_ + k0 + 32 * h + lkoff,
                  At[buf][h] + (16 * w) * 32);
    }
    // W: 64 rows x 2 khalves; wave w stages khalf w>>2, rows [(w&3)*16, +16)
    {
      int h = w >> 2;
      int r = (w & 3) * 16;
      gload_lds16(W + (size_t)(col0 + r + lrow) * DI_ + k0 + 32 * h + lkoff,
                  Wt[buf][h] + r * 32);
    }
  };
  auto compute = [&](int buf) {
    short8 af[2], bf[2][4];
#pragma unroll
    for (int h = 0; h < 2; ++h) {
      af[h] = *(const short8*)&At[buf][h][(16 * w + fr) * 32 + fq];
#pragma unroll
      for (int j = 0; j < 4; ++j)
        bf[h][j] = *(const short8*)&Wt[buf][h][(16 * j + fr) * 32 + fq];
    }
#pragma unroll
    for (int h = 0; h < 2; ++h)
#pragma unroll
      for (int j = 0; j < 4; ++j)
        acc[j] = __builtin_amdgcn_mfma_f32_16x16x32_bf16(af[h], bf[h][j], acc[j], 0, 0, 0);
  };

  stage(0, 0);
  __syncthreads();
  int cur = 0;
  for (int t = 0; t < 31; ++t) {
    stage(cur ^ 1, t + 1);
    compute(cur);
    __syncthreads();
    cur ^= 1;
  }
  compute(cur);

  const int rg = row0 + 16 * w + ((lane >> 4) << 2);
#pragma unroll
  for (int j = 0; j < 4; ++j) {
    int cg = col0 + 16 * j + (lane & 15);
#pragma unroll
    for (int r = 0; r < 4; ++r)
      out[(size_t)(rg + r) * DM_ + cg] = acc[j][r];
  }
}

// ---------------------------------------------------------------------------
// GEMM2 (bf16 MFMA, split-K, both dirs): part[dir][ks][m][n] in FP16.
// Single-barrier double-buffered pipeline.
// ---------------------------------------------------------------------------
__global__ __launch_bounds__(256) void gemm2_mfma_k(
    const unsigned short* __restrict__ xsbf, const unsigned short* __restrict__ xsbr,
    const unsigned short* __restrict__ Wxbf, const unsigned short* __restrict__ Wxbr,
    unsigned short* __restrict__ part)
{
  __shared__ unsigned short At[2][128 * 32];
  __shared__ unsigned short Wt[2][64 * 32];
  const int tid  = threadIdx.x;
  const int w    = tid >> 6;
  const int lane = tid & 63;
  const int ks   = blockIdx.x;
  const int row0 = blockIdx.y * 128;
  const int dir  = blockIdx.z;
  const unsigned short* A = dir ? xsbr : xsbf;
  const unsigned short* W = dir ? Wxbr : Wxbf;
  const int kbase = ks * (DI_ / KS_);
  const int lrow  = lane >> 2;
  const int lkoff = (lane & 3) * 8;
  const int fr = lane & 15;
  const int fq = (lane >> 4) * 8;

  floatx4 acc[2][4];
#pragma unroll
  for (int i = 0; i < 2; ++i)
#pragma unroll
    for (int j = 0; j < 4; ++j)
#pragma unroll
      for (int r = 0; r < 4; ++r) acc[i][j][r] = 0.f;

  auto stage = [&](int buf, int k0) {
#pragma unroll
    for (int j = 0; j < 2; ++j) {
      int r = w * 32 + j * 16;
      gload_lds16(A + (size_t)(row0 + r + lrow) * DI_ + kbase + k0 + lkoff, At[buf] + r * 32);
    }
    int r = w * 16;
    gload_lds16(W + (size_t)(r + lrow) * DI_ + kbase + k0 + lkoff, Wt[buf] + r * 32);
  };
  auto compute = [&](int buf) {
    short8 af[2], bf[4];
#pragma unroll
    for (int i = 0; i < 2; ++i)
      af[i] = *(const short8*)&At[buf][(32 * w + 16 * i + fr) * 32 + fq];
#pragma unroll
    for (int j = 0; j < 4; ++j)
      bf[j] = *(const short8*)&Wt[buf][(16 * j + fr) * 32 + fq];
#pragma unroll
    for (int i = 0; i < 2; ++i)
#pragma unroll
      for (int j = 0; j < 4; ++j)
        acc[i][j] = __builtin_amdgcn_mfma_f32_16x16x32_bf16(af[i], bf[j], acc[i][j], 0, 0, 0);
  };

  const int NT = (DI_ / KS_) >> 5;   // 4
  stage(0, 0);
  __syncthreads();
  int cur = 0;
  for (int t = 0; t < NT - 1; ++t) {
    stage(cur ^ 1, (t + 1) << 5);
    compute(cur);
    __syncthreads();
    cur ^= 1;
  }
  compute(cur);

  unsigned short* dst = part + (((size_t)dir * KS_ + ks) * M_) * 64;
#pragma unroll
  for (int i = 0; i < 2; ++i) {
    int rg = row0 + 32 * w + 16 * i + ((lane >> 4) << 2);
#pragma unroll
    for (int j = 0; j < 4; ++j) {
      int cg = 16 * j + (lane & 15);
#pragma unroll
      for (int r = 0; r < 4; ++r)
        dst[(size_t)(rg + r) * 64 + cg] = f2h(acc[i][j][r]);
    }
  }
}

// Reduce split-K fp16 partials: xd[dir][m][n] = sum_ks part[dir][ks][m][n].
// Also emits dt_raw (cols 0..31) as bf16 for the MFMA GEMM3.
__global__ __launch_bounds__(256) void reduce_part_k(
    const unsigned short* __restrict__ part, float* __restrict__ xdf, float* __restrict__ xdr,
    unsigned short* __restrict__ drbf, unsigned short* __restrict__ drbr)
{
  int g = blockIdx.x * 256 + threadIdx.x;
  int n4  = g & 15;
  int m   = (g >> 4) & (M_ - 1);
  int dir = g >> 16;
  const unsigned short* p = part + ((size_t)dir * KS_ * M_ + m) * 64 + n4 * 4;
  float4 s = make_float4(0.f, 0.f, 0.f, 0.f);
#pragma unroll
  for (int ks = 0; ks < KS_; ++ks) {
    ushort4 v = *(const ushort4*)(p + (size_t)ks * M_ * 64);
    s.x += h2f(v.x); s.y += h2f(v.y); s.z += h2f(v.z); s.w += h2f(v.w);
  }
  float* xd = dir ? xdr : xdf;
  *(float4*)(xd + (size_t)m * 64 + n4 * 4) = s;
  if (n4 < 8) {   // dt_raw columns 0..31 -> bf16
    unsigned short* dr = dir ? drbr : drbf;
    ushort4 o;
    o.x = f2bf(s.x); o.y = f2bf(s.y); o.z = f2bf(s.z); o.w = f2bf(s.w);
    *(ushort4*)(dr + (size_t)m * 32 + n4 * 4) = o;
  }
}

// ---------------------------------------------------------------------------
// Fused fp32 -> bf16 cast of 9 tensors + Atab precompute:
// Atab[dir][d][s] = -exp(Alog[d][s]) * log2(e)   (used by all scan kernels)
// ---------------------------------------------------------------------------
struct CastArgs {
  const float* src[9];
  unsigned short* dst[9];
  int start[9];
  int n[9];
};

__global__ __launch_bounds__(256) void cast_multi_k(
    CastArgs a, int total4,
    const float* __restrict__ Alf, const float* __restrict__ Alr,
    float* __restrict__ Atf, float* __restrict__ Atr)
{
  int g = blockIdx.x * 256 + threadIdx.x;
  if (g >= total4) return;
  if (g < 8192) {   // 2 * 1024 * 16 / 4 float4's of Atab
    const float* Al = (g < 4096) ? Alf : Alr;
    float* At = (g < 4096) ? Atf : Atr;
    int off = (g & 4095) * 4;
    float4 v = *(const float4*)(Al + off);
    float4 o = make_float4(-__expf(v.x) * LOG2E_, -__expf(v.y) * LOG2E_,
                           -__expf(v.z) * LOG2E_, -__expf(v.w) * LOG2E_);
    *(float4*)(At + off) = o;
  }
  int e = g * 4;
#pragma unroll 1
  for (int s = 0; s < 9; ++s) {
    if (e < a.start[s] + a.n[s]) {
      int off = e - a.start[s];
      float4 v = *(const float4*)(a.src[s] + off);
      ushort4 o;
      o.x = f2bf(v.x); o.y = f2bf(v.y); o.z = f2bf(v.z); o.w = f2bf(v.w);
      *(ushort4*)(a.dst[s] + off) = o;
      return;
    }
  }
}

// ---------------------------------------------------------------------------
// GEMM3 (bf16 MFMA, both dirs via grid.z): dt = softplus(dt_raw . Wdt^T + dtb)
// K=32 == one 16x16x32 MFMA. 128x128 tile, 4 waves x (4x4) tiles, one K-step.
// OUTPUT fp16 (dt feeds exp2(dt*A); 2^-11 relative error is harmless).
// ---------------------------------------------------------------------------
__global__ __launch_bounds__(256) void gemm3_mfma_k(
    const unsigned short* __restrict__ drbf, const unsigned short* __restrict__ drbr,
    const unsigned short* __restrict__ Wdtbf, const unsigned short* __restrict__ Wdtbr,
    const float* __restrict__ b0, const float* __restrict__ b1,
    unsigned short* __restrict__ C0, unsigned short* __restrict__ C1)
{
  __shared__ unsigned short At[128 * 32];
  __shared__ unsigned short Wt[128 * 32];
  const unsigned short* A = blockIdx.z ? drbr : drbf;
  const unsigned short* W = blockIdx.z ? Wdtbr : Wdtbf;
  const float* bias = blockIdx.z ? b1 : b0;
  unsigned short* C = blockIdx.z ? C1 : C0;
  const int tid  = threadIdx.x;
  const int w    = tid >> 6;
  const int lane = tid & 63;
  const int wm   = w >> 1, wn = w & 1;
  const int row0 = blockIdx.y * 128, col0 = blockIdx.x * 128;
  const int lrow  = lane >> 2;
  const int lkoff = (lane & 3) * 8;
  const int fr = lane & 15;
  const int fq = (lane >> 4) * 8;

#pragma unroll
  for (int j = 0; j < 2; ++j) {
    int r = w * 32 + j * 16;
    gload_lds16(A + (size_t)(row0 + r + lrow) * DTR_ + lkoff, At + r * 32);
    gload_lds16(W + (size_t)(col0 + r + lrow) * DTR_ + lkoff, Wt + r * 32);
  }
  __syncthreads();
  short8 af[4], bf[4];
#pragma unroll
  for (int i = 0; i < 4; ++i) {
    af[i] = *(const short8*)&At[(64 * wm + 16 * i + fr) * 32 + fq];
    bf[i] = *(const short8*)&Wt[(64 * wn + 16 * i + fr) * 32 + fq];
  }
  floatx4 acc[4][4];
#pragma unroll
  for (int i = 0; i < 4; ++i)
#pragma unroll
    for (int j = 0; j < 4; ++j) {
#pragma unroll
      for (int r = 0; r < 4; ++r) acc[i][j][r] = 0.f;
      acc[i][j] = __builtin_amdgcn_mfma_f32_16x16x32_bf16(af[i], bf[j], acc[i][j], 0, 0, 0);
    }
#pragma unroll
  for (int i = 0; i < 4; ++i) {
    int rg = row0 + 64 * wm + 16 * i + ((lane >> 4) << 2);
#pragma unroll
    for (int j = 0; j < 4; ++j) {
      int cg = col0 + 64 * wn + 16 * j + (lane & 15);
      float bv = bias[cg];
#pragma unroll
      for (int r = 0; r < 4; ++r) {
        float v = acc[i][j][r] + bv;
        float e = fexp2(-fabsf(v) * LOG2E_);
        float sp = fmaxf(v, 0.f) + LN2_ * flog2(1.f + e);
        C[(size_t)(rg + r) * DI_ + cg] = f2h(sp);
      }
    }
  }
}

// ---------------------------------------------------------------------------
// Depthwise conv(4) + bias + SiLU, both directions; bf16 in (xz) / bf16 out.
// EIGHT timesteps per block: 11 input rows feed 8 outputs, weights loaded once.
// Per-output tap order (j ascending) preserved -> bitwise identical.
// ---------------------------------------------------------------------------
__global__ __launch_bounds__(256) void conv_silu_k(
    const unsigned short* __restrict__ xzbf, const unsigned short* __restrict__ xzbr,
    const float* __restrict__ cwf, const float* __restrict__ cbf,
    const float* __restrict__ cwr, const float* __restrict__ cbr,
    unsigned short* __restrict__ xsbf, unsigned short* __restrict__ xsbr)
{
  int bid = blockIdx.x;                 // [dir][b][t>>3]
  int tg  = bid & (L_ / 8 - 1);
  int b   = (bid >> 8) & (B_ - 1);
  int dir = bid >> 9;
  int t   = tg << 3;
  const unsigned short* xz = dir ? xzbr : xzbf;
  const float* cw = dir ? cwr : cwf;
  const float* cb = dir ? cbr : cbf;
  unsigned short* xsb = dir ? xsbr : xsbf;
  int d0 = threadIdx.x << 2;
  float wv[4][4];
#pragma unroll
  for (int i = 0; i < 4; ++i) {
    float4 w4 = *(const float4*)(cw + (size_t)(d0 + i) * 4);
    wv[i][0] = w4.x; wv[i][1] = w4.y; wv[i][2] = w4.z; wv[i][3] = w4.w;
  }
  float4 cbv = *(const float4*)(cb + d0);
  float acc[8][4];   // [k = output t+k][i = channel]
#pragma unroll
  for (int k = 0; k < 8; ++k) {
    acc[k][0] = cbv.x; acc[k][1] = cbv.y; acc[k][2] = cbv.z; acc[k][3] = cbv.w;
  }
#pragma unroll
  for (int m = 0; m < 11; ++m) {
    int tt = dir ? (t + 10 - m) : (t - 3 + m);
    if (tt >= 0 && tt < L_) {
      ushort4 v = *(const ushort4*)(xz + ((size_t)b * L_ + tt) * 2048 + d0);
      float f0 = bf2f(v.x), f1 = bf2f(v.y), f2 = bf2f(v.z), f3 = bf2f(v.w);
#pragma unroll
      for (int k = 0; k < 8; ++k) {
        int j = dir ? (m - 7 + k) : (m - k);
        if (j >= 0 && j < 4) {
          acc[k][0] = fmaf(wv[0][j], f0, acc[k][0]);
          acc[k][1] = fmaf(wv[1][j], f1, acc[k][1]);
          acc[k][2] = fmaf(wv[2][j], f2, acc[k][2]);
          acc[k][3] = fmaf(wv[3][j], f3, acc[k][3]);
        }
      }
    }
  }
#pragma unroll
  for (int k = 0; k < 8; ++k) {
    ushort4 o;
#pragma unroll
    for (int i = 0; i < 4; ++i) {
      float s = acc[k][i] * __builtin_amdgcn_rcpf(1.f + fexp2(-acc[k][i] * LOG2E_));
      ((unsigned short*)&o)[i] = f2bf(s);
    }
    *(ushort4*)(xsb + ((size_t)b * L_ + (t + k)) * DI_ + d0) = o;
  }
}

// ---------------------------------------------------------------------------
// Scan pass A: per (dir,b,d,chunk): E = local end state (fp16), dts = sum dt.
// dt is fp16; A-table precomputed.
// ---------------------------------------------------------------------------
__global__ __launch_bounds__(256) void scan_passA_k(
    const unsigned short* __restrict__ dtf, const unsigned short* __restrict__ dtr,
    const unsigned short* __restrict__ xsbf, const unsigned short* __restrict__ xsbr,
    const float* __restrict__ xdf, const float* __restrict__ xdr,
    const float* __restrict__ Atabf, const float* __restrict__ Atabr,
    unsigned short* __restrict__ E, float* __restrict__ dts)
{
  __shared__ float bS[CL_][16];         // B row per chunk step
  int bid  = blockIdx.x;               // [dir][b][c][dgrp]
  int dgrp = bid & 3;
  int c    = (bid >> 2) & (NC_ - 1);
  int b    = (bid >> 8) & 1;
  int dir  = bid >> 9;
  int d    = (dgrp << 8) + threadIdx.x;
  const unsigned short* dt = dir ? dtr : dtf;
  const unsigned short* xs = dir ? xsbr : xsbf;
  const float* xd = dir ? xdr : xdf;
  const float* At = dir ? Atabr : Atabf;
  if (threadIdx.x < CL_ * 4) {
    int li = threadIdx.x >> 2;
    int lc = threadIdx.x & 3;
    *(float4*)&bS[li][lc * 4] =
        *(const float4*)(xd + ((size_t)b * L_ + c * CL_ + li) * 64 + 32 + lc * 4);
  }
  float Ai2[16];
#pragma unroll
  for (int q = 0; q < 4; ++q) {
    float4 a4 = *(const float4*)(At + (size_t)d * 16 + q * 4);
    Ai2[4*q] = a4.x; Ai2[4*q+1] = a4.y; Ai2[4*q+2] = a4.z; Ai2[4*q+3] = a4.w;
  }
  float h[16];
#pragma unroll
  for (int s = 0; s < 16; ++s) h[s] = 0.f;
  int t0 = c * CL_ + (dir ? CL_ - 1 : 0);
  const long sdt = (dir ? -1L : 1L) * DI_;
  const unsigned short* dtp = dt + ((size_t)b * L_ + t0) * DI_ + d;
  const unsigned short* xsp = xs + ((size_t)b * L_ + t0) * DI_ + d;
  float dtsum = 0.f;
  __syncthreads();
#pragma unroll 2
  for (int i = 0; i < CL_; ++i) {
    int row = dir ? (CL_ - 1 - i) : i;
    float dtv = h2f(*dtp);
    float xv  = bf2f(*xsp);
    float Bv[16];
#pragma unroll
    for (int q = 0; q < 4; ++q) {
      float4 bq = *(const float4*)&bS[row][4 * q];
      Bv[4*q] = bq.x; Bv[4*q+1] = bq.y; Bv[4*q+2] = bq.z; Bv[4*q+3] = bq.w;
    }
    float dtx = dtv * xv;
    dtsum += dtv;
#pragma unroll
    for (int s = 0; s < 16; ++s) {
      float dA = fexp2(dtv * Ai2[s]);
      h[s] = fmaf(dA, h[s], dtx * Bv[s]);
    }
    dtp += sdt; xsp += sdt;
  }
  size_t base = ((((size_t)dir * B_ + b) * NC_ + c) * DI_ + d) * 16;
  unsigned pk[8];
#pragma unroll
  for (int q = 0; q < 8; ++q)
    pk[q] = (unsigned)f2h(h[2*q]) | ((unsigned)f2h(h[2*q+1]) << 16);
  *(uint4*)(E + base)     = make_uint4(pk[0], pk[1], pk[2], pk[3]);
  *(uint4*)(E + base + 8) = make_uint4(pk[4], pk[5], pk[6], pk[7]);
  dts[(((size_t)dir * B_ + b) * NC_ + c) * DI_ + d] = dtsum;
}

// ---------------------------------------------------------------------------
// Chunk prefix: Hin[c] = state entering chunk c (fp16 storage, fp32 chain).
// 8-wide batched loads hide L2/L3 latency across the serial fma chain.
// ---------------------------------------------------------------------------
__global__ __launch_bounds__(256) void scan_prefix_k(
    const unsigned short* __restrict__ E, const float* __restrict__ dts,
    const float* __restrict__ Atabf, const float* __restrict__ Atabr,
    unsigned short* __restrict__ Hin)
{
  int gid = blockIdx.x * 256 + threadIdx.x;   // [dir][b][d][s]
  int s   = gid & 15;
  int d   = (gid >> 4) & (DI_ - 1);
  int b   = (gid >> 14) & 1;
  int dir = gid >> 15;
  float Ai2 = (dir ? Atabr : Atabf)[(size_t)d * 16 + s];
  size_t eb  = (((size_t)dir * B_ + b) * NC_) * DI_ * 16 + (size_t)d * 16 + s;
  size_t db2 = (((size_t)dir * B_ + b) * NC_) * DI_ + d;
  const size_t es = (size_t)DI_ * 16;
  float h = 0.f;
  if (!dir) {
    size_t idx = eb;
    size_t di  = db2;
#pragma unroll 1
    for (int cb = 0; cb < NC_; cb += 8) {
      unsigned short Ev[8]; float dv[8];
#pragma unroll
      for (int k = 0; k < 8; ++k) {
        Ev[k] = E[idx + (size_t)k * es];
        dv[k] = dts[di + (size_t)k * DI_];
      }
#pragma unroll
      for (int k = 0; k < 8; ++k) {
        Hin[idx + (size_t)k * es] = f2h(h);
        h = fmaf(fexp2(dv[k] * Ai2), h, h2f(Ev[k]));
      }
      idx += 8 * es; di += 8 * (size_t)DI_;
    }
  } else {
    size_t idx = eb + (size_t)(NC_ - 1) * es;
    size_t di  = db2 + (size_t)(NC_ - 1) * DI_;
#pragma unroll 1
    for (int cb = 0; cb < NC_; cb += 8) {
      unsigned short Ev[8]; float dv[8];
#pragma unroll
      for (int k = 0; k < 8; ++k) {
        Ev[k] = E[idx - (size_t)k * es];
        dv[k] = dts[di - (size_t)k * DI_];
      }
#pragma unroll
      for (int k = 0; k < 8; ++k) {
        Hin[idx - (size_t)k * es] = f2h(h);
        h = fmaf(fexp2(dv[k] * Ai2), h, h2f(Ev[k]));
      }
      idx -= 8 * es; di -= 8 * (size_t)DI_;
    }
  }
}

// ---------------------------------------------------------------------------
// Scan pass C: replay chunk from Hin (fp16), y = (sum h*C + xs*Dp)*silu(z)
// dt is fp16; A-table precomputed.
// ---------------------------------------------------------------------------
__global__ __launch_bounds__(256) void scan_passC_k(
    const unsigned short* __restrict__ dtf, const unsigned short* __restrict__ dtr,
    const unsigned short* __restrict__ xsbf, const unsigned short* __restrict__ xsbr,
    const float* __restrict__ xdf, const float* __restrict__ xdr,
    const unsigned short* __restrict__ xzbf, const unsigned short* __restrict__ xzbr,
    const float* __restrict__ Atabf, const float* __restrict__ Atabr,
    const float* __restrict__ Dpf, const float* __restrict__ Dpr,
    const unsigned short* __restrict__ Hin,
    unsigned short* __restrict__ ybf, unsigned short* __restrict__ ybr)
{
  __shared__ float bcS[CL_][32];        // B(16)+C(16) per chunk step
  int bid  = blockIdx.x;
  int dgrp = bid & 3;
  int c    = (bid >> 2) & (NC_ - 1);
  int b    = (bid >> 8) & 1;
  int dir  = bid >> 9;
  int d    = (dgrp << 8) + threadIdx.x;
  const unsigned short* dt  = dir ? dtr : dtf;
  const unsigned short* xs = dir ? xsbr : xsbf;
  const float* xd  = dir ? xdr : xdf;
  const unsigned short* xz = dir ? xzbr : xzbf;
  const float* At  = dir ? Atabr : Atabf;
  unsigned short* yb = dir ? ybr : ybf;
  float Dpv = (dir ? Dpr : Dpf)[d];
  {
    int li = threadIdx.x >> 3;
    int lc = threadIdx.x & 7;
    *(float4*)&bcS[li][lc * 4] =
        *(const float4*)(xd + ((size_t)b * L_ + c * CL_ + li) * 64 + 32 + lc * 4);
  }
  float Ai2[16];
#pragma unroll
  for (int q = 0; q < 4; ++q) {
    float4 a4 = *(const float4*)(At + (size_t)d * 16 + q * 4);
    Ai2[4*q] = a4.x; Ai2[4*q+1] = a4.y; Ai2[4*q+2] = a4.z; Ai2[4*q+3] = a4.w;
  }
  size_t hb = ((((size_t)dir * B_ + b) * NC_ + c) * DI_ + d) * 16;
  float h[16];
  {
    uint4 ha = *(const uint4*)(Hin + hb);
    uint4 hbv = *(const uint4*)(Hin + hb + 8);
    unsigned hw[8] = {ha.x, ha.y, ha.z, ha.w, hbv.x, hbv.y, hbv.z, hbv.w};
#pragma unroll
    for (int q = 0; q < 8; ++q) {
      h[2*q]   = h2f((unsigned short)(hw[q] & 0xffffu));
      h[2*q+1] = h2f((unsigned short)(hw[q] >> 16));
    }
  }
  int t0 = c * CL_ + (dir ? CL_ - 1 : 0);
  const long sdt = (dir ? -1L : 1L) * DI_;
  const long sz_ = (dir ? -1L : 1L) * 2048;
  const unsigned short* dtp = dt + ((size_t)b * L_ + t0) * DI_ + d;
  const unsigned short* xsp = xs + ((size_t)b * L_ + t0) * DI_ + d;
  const unsigned short* zp = xz + ((size_t)b * L_ + t0) * 2048 + DI_ + d;
  unsigned short* ybp = yb + ((size_t)b * L_ + t0) * DI_ + d;
  __syncthreads();
#pragma unroll 2
  for (int i = 0; i < CL_; ++i) {
    int row = dir ? (CL_ - 1 - i) : i;
    float dtv = h2f(*dtp);
    float xv  = bf2f(*xsp);
    float z   = bf2f(*zp);
    float Bv[16], Cv[16];
#pragma unroll
    for (int q = 0; q < 4; ++q) {
      float4 bq = *(const float4*)&bcS[row][4 * q];
      float4 cq = *(const float4*)&bcS[row][16 + 4 * q];
      Bv[4*q] = bq.x; Bv[4*q+1] = bq.y; Bv[4*q+2] = bq.z; Bv[4*q+3] = bq.w;
      Cv[4*q] = cq.x; Cv[4*q+1] = cq.y; Cv[4*q+2] = cq.z; Cv[4*q+3] = cq.w;
    }
    float dtx = dtv * xv;
    float yacc = 0.f;
#pragma unroll
    for (int s = 0; s < 16; ++s) {
      float dA = fexp2(dtv * Ai2[s]);
      h[s] = fmaf(dA, h[s], dtx * Bv[s]);
      yacc = fmaf(h[s], Cv[s], yacc);
    }
    float yv = fmaf(xv, Dpv, yacc);
    float sz = z * __builtin_amdgcn_rcpf(1.f + fexp2(-z * LOG2E_));
    *ybp = f2bf(yv * sz);
    dtp += sdt; xsp += sdt; zp += sz_; ybp += sdt;
  }
}

// ---------------------------------------------------------------------------
extern "C" void kernel_launch(void* const* d_in, const int* in_sizes, int n_in,
                              void* d_out, int out_size, void* d_ws, size_t ws_size,
                              hipStream_t stream)
{
  const float* x       = (const float*)d_in[0];
  const float* Win_f   = (const float*)d_in[1];
  const float* convw_f = (const float*)d_in[2];
  const float* convb_f = (const float*)d_in[3];
  const float* Wx_f    = (const float*)d_in[4];
  const float* Wdt_f   = (const float*)d_in[5];
  const float* dtb_f   = (const float*)d_in[6];
  const float* Alog_f  = (const float*)d_in[7];
  const float* Dp_f    = (const float*)d_in[8];
  const float* Wout_f  = (const float*)d_in[9];
  const float* Win_r   = (const float*)d_in[10];
  const float* convw_r = (const float*)d_in[11];
  const float* convb_r = (const float*)d_in[12];
  const float* Wx_r    = (const float*)d_in[13];
  const float* Wdt_r   = (const float*)d_in[14];
  const float* dtb_r   = (const float*)d_in[15];
  const float* Alog_r  = (const float*)d_in[16];
  const float* Dp_r    = (const float*)d_in[17];
  const float* Wout_r  = (const float*)d_in[18];
  float* out = (float*)d_out;

  float* ws  = (float*)d_ws;
  float* xdf = ws;
  float* xdr = xdf + (size_t)M_ * 64;
  unsigned short* dtf = (unsigned short*)(xdr + (size_t)M_ * 64);   // fp16 dt
  unsigned short* dtr = dtf + (size_t)M_ * DI_;
  // E/Hin fp16 (8.4 MB each); fp16 part2 (8.4 MB) aliases Eh, dead before passA
  unsigned short* Eh = dtr + (size_t)M_ * DI_;
  unsigned short* Hh = Eh + (size_t)2 * B_ * NC_ * DI_ * 16;
  float* dtsb = (float*)(Hh + (size_t)2 * B_ * NC_ * DI_ * 16);
  unsigned short* part2 = Eh;
  unsigned short* xzbf    = (unsigned short*)(dtsb + (size_t)2 * B_ * NC_ * DI_);
  unsigned short* xzbr    = xzbf + (size_t)M_ * 2048;
  unsigned short* xb      = xzbr + (size_t)M_ * 2048;
  unsigned short* Winb_f  = xb + (size_t)M_ * DM_;
  unsigned short* Winb_r  = Winb_f + (size_t)2048 * DM_;
  unsigned short* Woutb_f = Winb_r + (size_t)2048 * DM_;
  unsigned short* Woutb_r = Woutb_f + (size_t)DM_ * DI_;
  unsigned short* ybf     = Woutb_r + (size_t)DM_ * DI_;
  unsigned short* ybr     = ybf + (size_t)M_ * DI_;
  unsigned short* xsbf    = ybr + (size_t)M_ * DI_;
  unsigned short* xsbr    = xsbf + (size_t)M_ * DI_;
  unsigned short* Wxb_f   = xsbr + (size_t)M_ * DI_;
  unsigned short* Wxb_r   = Wxb_f + (size_t)64 * DI_;
  unsigned short* Wdtb_f  = Wxb_r + (size_t)64 * DI_;
  unsigned short* Wdtb_r  = Wdtb_f + (size_t)DI_ * DTR_;
  unsigned short* drbf    = Wdtb_r + (size_t)DI_ * DTR_;
  unsigned short* drbr    = drbf + (size_t)M_ * DTR_;
  float* Atabf = (float*)(drbr + (size_t)M_ * DTR_);     // [d][s] fp32
  float* Atabr = Atabf + (size_t)DI_ * DS_;

  dim3 blk(256);

  // cast x, Win_f/r, Wout_f/r, Wx_f/r, Wdt_f/r to bf16; precompute Atab
  {
    CastArgs ca;
    ca.src[0] = x;      ca.dst[0] = xb;      ca.n[0] = M_ * DM_;
    ca.src[1] = Win_f;  ca.dst[1] = Winb_f;  ca.n[1] = 2048 * DM_;
    ca.src[2] = Win_r;  ca.dst[2] = Winb_r;  ca.n[2] = 2048 * DM_;
    ca.src[3] = Wout_f; ca.dst[3] = Woutb_f; ca.n[3] = DM_ * DI_;
    ca.src[4] = Wout_r; ca.dst[4] = Woutb_r; ca.n[4] = DM_ * DI_;
    ca.src[5] = Wx_f;   ca.dst[5] = Wxb_f;   ca.n[5] = 64 * DI_;
    ca.src[6] = Wx_r;   ca.dst[6] = Wxb_r;   ca.n[6] = 64 * DI_;
    ca.src[7] = Wdt_f;  ca.dst[7] = Wdtb_f;  ca.n[7] = DI_ * DTR_;
    ca.src[8] = Wdt_r;  ca.dst[8] = Wdtb_r;  ca.n[8] = DI_ * DTR_;
    int st = 0;
    for (int s = 0; s < 9; ++s) { ca.start[s] = st; st += ca.n[s]; }
    int total4 = st / 4;
    cast_multi_k<<<(total4 + 255) / 256, blk, 0, stream>>>(
        ca, total4, Alog_f, Alog_r, Atabf, Atabr);
  }

  // GEMM1 (bf16 MFMA, dirs fused): xz_f/xz_r = x . Win_f/r^T -> bf16
  gemm1_mfma_k<<<dim3(2048 / 128, M_ / 128), blk, 0, stream>>>(
      xb, Winb_f, Winb_r, xzbf, xzbr, 2048, DM_);

  // conv + silu (both dirs, 8 timesteps/block), bf16 in/out
  conv_silu_k<<<2 * B_ * (L_ / 8), blk, 0, stream>>>(xzbf, xzbr, convw_f, convb_f,
      convw_r, convb_r, xsbf, xsbr);

  // GEMM2 (bf16 MFMA split-K, both dirs, fp16 partials) + reduce
  gemm2_mfma_k<<<dim3(KS_, M_ / 128, 2), blk, 0, stream>>>(
      xsbf, xsbr, Wxb_f, Wxb_r, part2);
  reduce_part_k<<<(2 * M_ * 16) / 256, blk, 0, stream>>>(part2, xdf, xdr,
      drbf, drbr);

  // GEMM3 (bf16 MFMA, both dirs): dt = softplus(dt_raw . Wdt^T + dtb) -> fp16
  gemm3_mfma_k<<<dim3(DI_ / 128, M_ / 128, 2), blk, 0, stream>>>(
      drbf, drbr, Wdtb_f, Wdtb_r, dtb_f, dtb_r, dtf, dtr);

  // chunked scan (A -> prefix -> C), P recomputed from dtsum
  scan_passA_k<<<2 * B_ * NC_ * 4, blk, 0, stream>>>(dtf, dtr, xsbf, xsbr,
      xdf, xdr, Atabf, Atabr, Eh, dtsb);
  scan_prefix_k<<<(2 * B_ * DI_ * 16) / 256, blk, 0, stream>>>(
      Eh, dtsb, Atabf, Atabr, Hh);
  scan_passC_k<<<2 * B_ * NC_ * 4, blk, 0, stream>>>(dtf, dtr, xsbf, xsbr,
      xdf, xdr, xzbf, xzbr, Atabf, Atabr, Dp_f, Dp_r, Hh, ybf, ybr);

  // GEMM4 fused (both dirs + add): out = y_f.Wout_f^T + y_r.Wout_r^T
  gemm4_fused_k<<<dim3(DM_ / 64, M_ / 128), dim3(512), 0, stream>>>(
      ybf, Woutb_f, ybr, Woutb_r, out);
}

// Round 10
// 246.714 us; speedup vs baseline: 1.0077x; 1.0077x over previous
//
#include <hip/hip_runtime.h>
#include <cmath>

#define B_   2
#define L_   2048
#define DM_  512
#define DI_  1024
#define DS_  16
#define DTR_ 32
#define M_   (B_*L_)   // 4096
#define NC_  64        // chunks
#define CL_  32        // chunk length (NC_*CL_ == L_)
#define KS_  8         // GEMM2 split-K factor
#define LOG2E_ 1.44269504088896340736f
#define LN2_   0.69314718055994530942f

typedef __attribute__((ext_vector_type(8))) short short8;   // 8 bf16 = 4 VGPRs
typedef __attribute__((ext_vector_type(4))) float floatx4;  // MFMA acc

__device__ inline unsigned short f2bf(float f) {
  unsigned u = __float_as_uint(f);
  unsigned r = (u + 0x7fffu + ((u >> 16) & 1u)) >> 16;   // RNE
  return (unsigned short)r;
}
__device__ inline float bf2f(unsigned short u) {
  return __uint_as_float(((unsigned)u) << 16);
}
// fp16 pack/unpack (v_cvt_f16_f32 / v_cvt_f32_f16)
__device__ inline unsigned short f2h(float f) {
  _Float16 h = (_Float16)f;
  return *(unsigned short*)&h;
}
__device__ inline float h2f(unsigned short u) {
  _Float16 h = *(_Float16*)&u;
  return (float)h;
}
// raw v_exp_f32 (2^x) / v_log_f32 (log2 x) — libm exp2f/log1pf are slow multi-inst paths
__device__ inline float fexp2(float x) { return __builtin_amdgcn_exp2f(x); }
__device__ inline float flog2(float x) { return __builtin_amdgcn_logf(x); }

__device__ inline void gload_lds16(const unsigned short* g, unsigned short* l) {
  __builtin_amdgcn_global_load_lds(
      (const __attribute__((address_space(1))) void*)g,
      (__attribute__((address_space(3))) void*)l, 16, 0, 0);
}

// ---------------------------------------------------------------------------
// GEMM1 (bf16 MFMA, BOTH dirs fused): xz_f = x.Win_f^T, xz_r = x.Win_r^T.
// 3-deep buffer rotation + counted vmcnt(6) (T3/T4-lite): the barrier no
// longer drains the just-issued stage — its 6 loads stay in flight across
// the barrier; only the stage issued a full compute-phase ago must land.
// LDS 3 x 24KB = 72KB -> still 2 blocks/CU.
// ---------------------------------------------------------------------------
__global__ __launch_bounds__(256, 2) void gemm1_mfma_k(
    const unsigned short* __restrict__ A,
    const unsigned short* __restrict__ Wf, const unsigned short* __restrict__ Wr,
    unsigned short* __restrict__ Cf, unsigned short* __restrict__ Cr)
{
  __shared__ unsigned short At[3][128 * 32];
  __shared__ unsigned short Wtf[3][128 * 32];
  __shared__ unsigned short Wtr[3][128 * 32];
  const int tid  = threadIdx.x;
  const int w    = tid >> 6;
  const int lane = tid & 63;
  const int wm   = w >> 1, wn = w & 1;
  const int row0 = blockIdx.y * 128, col0 = blockIdx.x * 128;
  const int lrow  = lane >> 2;
  const int lkoff = (lane & 3) * 8;
  const int fr = lane & 15;
  const int fq = (lane >> 4) * 8;
  const int K = DM_;           // 512
  const int NT = K >> 5;       // 16

  floatx4 accf[4][4], accr[4][4];
#pragma unroll
  for (int i = 0; i < 4; ++i)
#pragma unroll
    for (int j = 0; j < 4; ++j)
#pragma unroll
      for (int r = 0; r < 4; ++r) { accf[i][j][r] = 0.f; accr[i][j][r] = 0.f; }

  auto stage = [&](int buf, int k0) {   // 6 vmem instructions per wave
#pragma unroll
    for (int j = 0; j < 2; ++j) {
      int r = w * 32 + j * 16;
      gload_lds16(A  + (size_t)(row0 + r + lrow) * K + k0 + lkoff, At[buf]  + r * 32);
      gload_lds16(Wf + (size_t)(col0 + r + lrow) * K + k0 + lkoff, Wtf[buf] + r * 32);
      gload_lds16(Wr + (size_t)(col0 + r + lrow) * K + k0 + lkoff, Wtr[buf] + r * 32);
    }
  };
  auto compute = [&](int buf) {
    short8 af[4], bff[4], bfr[4];
#pragma unroll
    for (int i = 0; i < 4; ++i) {
      af[i]  = *(const short8*)&At[buf][(64 * wm + 16 * i + fr) * 32 + fq];
      bff[i] = *(const short8*)&Wtf[buf][(64 * wn + 16 * i + fr) * 32 + fq];
      bfr[i] = *(const short8*)&Wtr[buf][(64 * wn + 16 * i + fr) * 32 + fq];
    }
#pragma unroll
    for (int i = 0; i < 4; ++i)
#pragma unroll
      for (int j = 0; j < 4; ++j) {
        accf[i][j] = __builtin_amdgcn_mfma_f32_16x16x32_bf16(af[i], bff[j], accf[i][j], 0, 0, 0);
        accr[i][j] = __builtin_amdgcn_mfma_f32_16x16x32_bf16(af[i], bfr[j], accr[i][j], 0, 0, 0);
      }
  };

  // prologue: two stages in flight; retire the first (keep 6 outstanding)
  stage(0, 0);
  stage(1, 32);
  asm volatile("s_waitcnt vmcnt(6)" ::: "memory");
  __builtin_amdgcn_s_barrier();
  __builtin_amdgcn_sched_barrier(0);
  // steady state: issue stage(t+2), compute(t), retire stage(t+1)'s loads
#pragma unroll 1
  for (int t = 0; t < NT - 2; ++t) {
    stage((t + 2) % 3, (t + 2) << 5);
    compute(t % 3);
    asm volatile("s_waitcnt vmcnt(6)" ::: "memory");
    __builtin_amdgcn_s_barrier();
    __builtin_amdgcn_sched_barrier(0);
  }
  // tail: t = NT-2 (no new stage; drain last stage), then t = NT-1
  compute((NT - 2) % 3);
  asm volatile("s_waitcnt vmcnt(0)" ::: "memory");
  __builtin_amdgcn_s_barrier();
  __builtin_amdgcn_sched_barrier(0);
  compute((NT - 1) % 3);

#pragma unroll
  for (int i = 0; i < 4; ++i) {
    int rg = row0 + 64 * wm + 16 * i + ((lane >> 4) << 2);
#pragma unroll
    for (int j = 0; j < 4; ++j) {
      int cg = col0 + 64 * wn + 16 * j + (lane & 15);
#pragma unroll
      for (int r = 0; r < 4; ++r) {
        Cf[(size_t)(rg + r) * 2048 + cg] = f2bf(accf[i][j][r]);
        Cr[(size_t)(rg + r) * 2048 + cg] = f2bf(accr[i][j][r]);
      }
    }
  }
}

// ---------------------------------------------------------------------------
// GEMM4 fused (bf16 MFMA): out = y_f . Wout_f^T + y_r . Wout_r^T  (fp32 out)
// 128x64 tile, 8 waves (512 thr, one 16-row band each). BK=64 as two [.][32]
// k-half subtiles, single-barrier double-buffered pipeline.
// ---------------------------------------------------------------------------
__global__ __launch_bounds__(512, 2) void gemm4_fused_k(
    const unsigned short* __restrict__ ybf, const unsigned short* __restrict__ Woutbf,
    const unsigned short* __restrict__ ybr, const unsigned short* __restrict__ Woutbr,
    float* __restrict__ out)
{
  __shared__ unsigned short At[2][2][128 * 32];   // [buf][khalf] 8KB each
  __shared__ unsigned short Wt[2][2][64 * 32];    // [buf][khalf] 4KB each
  const int tid  = threadIdx.x;
  const int w    = tid >> 6;          // 0..7
  const int lane = tid & 63;
  const int col0 = blockIdx.x * 64;
  const int row0 = blockIdx.y * 128;
  const int lrow  = lane >> 2;
  const int lkoff = (lane & 3) * 8;
  const int fr = lane & 15;
  const int fq = (lane >> 4) * 8;

  floatx4 acc[4];
#pragma unroll
  for (int j = 0; j < 4; ++j)
#pragma unroll
    for (int r = 0; r < 4; ++r) acc[j][r] = 0.f;

  // t in [0,32): src = t>>4, k0 = (t&15)*64
  auto stage = [&](int buf, int t) {
    const unsigned short* A = (t & 16) ? ybr : ybf;
    const unsigned short* W = (t & 16) ? Woutbr : Woutbf;
    const int k0 = (t & 15) << 6;
#pragma unroll
    for (int h = 0; h < 2; ++h) {
      gload_lds16(A + (size_t)(row0 + 16 * w + lrow) * DI_ + k0 + 32 * h + lkoff,
                  At[buf][h] + (16 * w) * 32);
    }
    {
      int h = w >> 2;
      int r = (w & 3) * 16;
      gload_lds16(W + (size_t)(col0 + r + lrow) * DI_ + k0 + 32 * h + lkoff,
                  Wt[buf][h] + r * 32);
    }
  };
  auto compute = [&](int buf) {
    short8 af[2], bf[2][4];
#pragma unroll
    for (int h = 0; h < 2; ++h) {
      af[h] = *(const short8*)&At[buf][h][(16 * w + fr) * 32 + fq];
#pragma unroll
      for (int j = 0; j < 4; ++j)
        bf[h][j] = *(const short8*)&Wt[buf][h][(16 * j + fr) * 32 + fq];
    }
#pragma unroll
    for (int h = 0; h < 2; ++h)
#pragma unroll
      for (int j = 0; j < 4; ++j)
        acc[j] = __builtin_amdgcn_mfma_f32_16x16x32_bf16(af[h], bf[h][j], acc[j], 0, 0, 0);
  };

  stage(0, 0);
  __syncthreads();
  int cur = 0;
  for (int t = 0; t < 31; ++t) {
    stage(cur ^ 1, t + 1);
    compute(cur);
    __syncthreads();
    cur ^= 1;
  }
  compute(cur);

  const int rg = row0 + 16 * w + ((lane >> 4) << 2);
#pragma unroll
  for (int j = 0; j < 4; ++j) {
    int cg = col0 + 16 * j + (lane & 15);
#pragma unroll
    for (int r = 0; r < 4; ++r)
      out[(size_t)(rg + r) * DM_ + cg] = acc[j][r];
  }
}

// ---------------------------------------------------------------------------
// GEMM2 (bf16 MFMA, split-K, both dirs): part[dir][ks][m][n] in FP16.
// Single-barrier double-buffered pipeline.
// ---------------------------------------------------------------------------
__global__ __launch_bounds__(256) void gemm2_mfma_k(
    const unsigned short* __restrict__ xsbf, const unsigned short* __restrict__ xsbr,
    const unsigned short* __restrict__ Wxbf, const unsigned short* __restrict__ Wxbr,
    unsigned short* __restrict__ part)
{
  __shared__ unsigned short At[2][128 * 32];
  __shared__ unsigned short Wt[2][64 * 32];
  const int tid  = threadIdx.x;
  const int w    = tid >> 6;
  const int lane = tid & 63;
  const int ks   = blockIdx.x;
  const int row0 = blockIdx.y * 128;
  const int dir  = blockIdx.z;
  const unsigned short* A = dir ? xsbr : xsbf;
  const unsigned short* W = dir ? Wxbr : Wxbf;
  const int kbase = ks * (DI_ / KS_);
  const int lrow  = lane >> 2;
  const int lkoff = (lane & 3) * 8;
  const int fr = lane & 15;
  const int fq = (lane >> 4) * 8;

  floatx4 acc[2][4];
#pragma unroll
  for (int i = 0; i < 2; ++i)
#pragma unroll
    for (int j = 0; j < 4; ++j)
#pragma unroll
      for (int r = 0; r < 4; ++r) acc[i][j][r] = 0.f;

  auto stage = [&](int buf, int k0) {
#pragma unroll
    for (int j = 0; j < 2; ++j) {
      int r = w * 32 + j * 16;
      gload_lds16(A + (size_t)(row0 + r + lrow) * DI_ + kbase + k0 + lkoff, At[buf] + r * 32);
    }
    int r = w * 16;
    gload_lds16(W + (size_t)(r + lrow) * DI_ + kbase + k0 + lkoff, Wt[buf] + r * 32);
  };
  auto compute = [&](int buf) {
    short8 af[2], bf[4];
#pragma unroll
    for (int i = 0; i < 2; ++i)
      af[i] = *(const short8*)&At[buf][(32 * w + 16 * i + fr) * 32 + fq];
#pragma unroll
    for (int j = 0; j < 4; ++j)
      bf[j] = *(const short8*)&Wt[buf][(16 * j + fr) * 32 + fq];
#pragma unroll
    for (int i = 0; i < 2; ++i)
#pragma unroll
      for (int j = 0; j < 4; ++j)
        acc[i][j] = __builtin_amdgcn_mfma_f32_16x16x32_bf16(af[i], bf[j], acc[i][j], 0, 0, 0);
  };

  const int NT = (DI_ / KS_) >> 5;   // 4
  stage(0, 0);
  __syncthreads();
  int cur = 0;
  for (int t = 0; t < NT - 1; ++t) {
    stage(cur ^ 1, (t + 1) << 5);
    compute(cur);
    __syncthreads();
    cur ^= 1;
  }
  compute(cur);

  unsigned short* dst = part + (((size_t)dir * KS_ + ks) * M_) * 64;
#pragma unroll
  for (int i = 0; i < 2; ++i) {
    int rg = row0 + 32 * w + 16 * i + ((lane >> 4) << 2);
#pragma unroll
    for (int j = 0; j < 4; ++j) {
      int cg = 16 * j + (lane & 15);
#pragma unroll
      for (int r = 0; r < 4; ++r)
        dst[(size_t)(rg + r) * 64 + cg] = f2h(acc[i][j][r]);
    }
  }
}

// Reduce split-K fp16 partials: xd[dir][m][n] = sum_ks part[dir][ks][m][n].
// Also emits dt_raw (cols 0..31) as bf16 for the MFMA GEMM3.
__global__ __launch_bounds__(256) void reduce_part_k(
    const unsigned short* __restrict__ part, float* __restrict__ xdf, float* __restrict__ xdr,
    unsigned short* __restrict__ drbf, unsigned short* __restrict__ drbr)
{
  int g = blockIdx.x * 256 + threadIdx.x;
  int n4  = g & 15;
  int m   = (g >> 4) & (M_ - 1);
  int dir = g >> 16;
  const unsigned short* p = part + ((size_t)dir * KS_ * M_ + m) * 64 + n4 * 4;
  float4 s = make_float4(0.f, 0.f, 0.f, 0.f);
#pragma unroll
  for (int ks = 0; ks < KS_; ++ks) {
    ushort4 v = *(const ushort4*)(p + (size_t)ks * M_ * 64);
    s.x += h2f(v.x); s.y += h2f(v.y); s.z += h2f(v.z); s.w += h2f(v.w);
  }
  float* xd = dir ? xdr : xdf;
  *(float4*)(xd + (size_t)m * 64 + n4 * 4) = s;
  if (n4 < 8) {   // dt_raw columns 0..31 -> bf16
    unsigned short* dr = dir ? drbr : drbf;
    ushort4 o;
    o.x = f2bf(s.x); o.y = f2bf(s.y); o.z = f2bf(s.z); o.w = f2bf(s.w);
    *(ushort4*)(dr + (size_t)m * 32 + n4 * 4) = o;
  }
}

// ---------------------------------------------------------------------------
// Fused fp32 -> bf16 cast of 9 tensors + Atab precompute:
// Atab[dir][d][s] = -exp(Alog[d][s]) * log2(e)   (used by all scan kernels)
// ---------------------------------------------------------------------------
struct CastArgs {
  const float* src[9];
  unsigned short* dst[9];
  int start[9];
  int n[9];
};

__global__ __launch_bounds__(256) void cast_multi_k(
    CastArgs a, int total4,
    const float* __restrict__ Alf, const float* __restrict__ Alr,
    float* __restrict__ Atf, float* __restrict__ Atr)
{
  int g = blockIdx.x * 256 + threadIdx.x;
  if (g >= total4) return;
  if (g < 8192) {   // 2 * 1024 * 16 / 4 float4's of Atab
    const float* Al = (g < 4096) ? Alf : Alr;
    float* At = (g < 4096) ? Atf : Atr;
    int off = (g & 4095) * 4;
    float4 v = *(const float4*)(Al + off);
    float4 o = make_float4(-__expf(v.x) * LOG2E_, -__expf(v.y) * LOG2E_,
                           -__expf(v.z) * LOG2E_, -__expf(v.w) * LOG2E_);
    *(float4*)(At + off) = o;
  }
  int e = g * 4;
#pragma unroll 1
  for (int s = 0; s < 9; ++s) {
    if (e < a.start[s] + a.n[s]) {
      int off = e - a.start[s];
      float4 v = *(const float4*)(a.src[s] + off);
      ushort4 o;
      o.x = f2bf(v.x); o.y = f2bf(v.y); o.z = f2bf(v.z); o.w = f2bf(v.w);
      *(ushort4*)(a.dst[s] + off) = o;
      return;
    }
  }
}

// ---------------------------------------------------------------------------
// GEMM3 (bf16 MFMA, both dirs via grid.z): dt = softplus(dt_raw . Wdt^T + dtb)
// K=32 == one 16x16x32 MFMA. 128x128 tile, 4 waves x (4x4) tiles, one K-step.
// OUTPUT fp16 (dt feeds exp2(dt*A); 2^-11 relative error is harmless).
// ---------------------------------------------------------------------------
__global__ __launch_bounds__(256) void gemm3_mfma_k(
    const unsigned short* __restrict__ drbf, const unsigned short* __restrict__ drbr,
    const unsigned short* __restrict__ Wdtbf, const unsigned short* __restrict__ Wdtbr,
    const float* __restrict__ b0, const float* __restrict__ b1,
    unsigned short* __restrict__ C0, unsigned short* __restrict__ C1)
{
  __shared__ unsigned short At[128 * 32];
  __shared__ unsigned short Wt[128 * 32];
  const unsigned short* A = blockIdx.z ? drbr : drbf;
  const unsigned short* W = blockIdx.z ? Wdtbr : Wdtbf;
  const float* bias = blockIdx.z ? b1 : b0;
  unsigned short* C = blockIdx.z ? C1 : C0;
  const int tid  = threadIdx.x;
  const int w    = tid >> 6;
  const int lane = tid & 63;
  const int wm   = w >> 1, wn = w & 1;
  const int row0 = blockIdx.y * 128, col0 = blockIdx.x * 128;
  const int lrow  = lane >> 2;
  const int lkoff = (lane & 3) * 8;
  const int fr = lane & 15;
  const int fq = (lane >> 4) * 8;

#pragma unroll
  for (int j = 0; j < 2; ++j) {
    int r = w * 32 + j * 16;
    gload_lds16(A + (size_t)(row0 + r + lrow) * DTR_ + lkoff, At + r * 32);
    gload_lds16(W + (size_t)(col0 + r + lrow) * DTR_ + lkoff, Wt + r * 32);
  }
  __syncthreads();
  short8 af[4], bf[4];
#pragma unroll
  for (int i = 0; i < 4; ++i) {
    af[i] = *(const short8*)&At[(64 * wm + 16 * i + fr) * 32 + fq];
    bf[i] = *(const short8*)&Wt[(64 * wn + 16 * i + fr) * 32 + fq];
  }
  floatx4 acc[4][4];
#pragma unroll
  for (int i = 0; i < 4; ++i)
#pragma unroll
    for (int j = 0; j < 4; ++j) {
#pragma unroll
      for (int r = 0; r < 4; ++r) acc[i][j][r] = 0.f;
      acc[i][j] = __builtin_amdgcn_mfma_f32_16x16x32_bf16(af[i], bf[j], acc[i][j], 0, 0, 0);
    }
#pragma unroll
  for (int i = 0; i < 4; ++i) {
    int rg = row0 + 64 * wm + 16 * i + ((lane >> 4) << 2);
#pragma unroll
    for (int j = 0; j < 4; ++j) {
      int cg = col0 + 64 * wn + 16 * j + (lane & 15);
      float bv = bias[cg];
#pragma unroll
      for (int r = 0; r < 4; ++r) {
        float v = acc[i][j][r] + bv;
        float e = fexp2(-fabsf(v) * LOG2E_);
        float sp = fmaxf(v, 0.f) + LN2_ * flog2(1.f + e);
        C[(size_t)(rg + r) * DI_ + cg] = f2h(sp);
      }
    }
  }
}

// ---------------------------------------------------------------------------
// Depthwise conv(4) + bias + SiLU, both directions; bf16 in (xz) / bf16 out.
// EIGHT timesteps per block: 11 input rows feed 8 outputs, weights loaded once.
// Per-output tap order (j ascending) preserved -> bitwise identical.
// ---------------------------------------------------------------------------
__global__ __launch_bounds__(256) void conv_silu_k(
    const unsigned short* __restrict__ xzbf, const unsigned short* __restrict__ xzbr,
    const float* __restrict__ cwf, const float* __restrict__ cbf,
    const float* __restrict__ cwr, const float* __restrict__ cbr,
    unsigned short* __restrict__ xsbf, unsigned short* __restrict__ xsbr)
{
  int bid = blockIdx.x;                 // [dir][b][t>>3]
  int tg  = bid & (L_ / 8 - 1);
  int b   = (bid >> 8) & (B_ - 1);
  int dir = bid >> 9;
  int t   = tg << 3;
  const unsigned short* xz = dir ? xzbr : xzbf;
  const float* cw = dir ? cwr : cwf;
  const float* cb = dir ? cbr : cbf;
  unsigned short* xsb = dir ? xsbr : xsbf;
  int d0 = threadIdx.x << 2;
  float wv[4][4];
#pragma unroll
  for (int i = 0; i < 4; ++i) {
    float4 w4 = *(const float4*)(cw + (size_t)(d0 + i) * 4);
    wv[i][0] = w4.x; wv[i][1] = w4.y; wv[i][2] = w4.z; wv[i][3] = w4.w;
  }
  float4 cbv = *(const float4*)(cb + d0);
  float acc[8][4];   // [k = output t+k][i = channel]
#pragma unroll
  for (int k = 0; k < 8; ++k) {
    acc[k][0] = cbv.x; acc[k][1] = cbv.y; acc[k][2] = cbv.z; acc[k][3] = cbv.w;
  }
#pragma unroll
  for (int m = 0; m < 11; ++m) {
    int tt = dir ? (t + 10 - m) : (t - 3 + m);
    if (tt >= 0 && tt < L_) {
      ushort4 v = *(const ushort4*)(xz + ((size_t)b * L_ + tt) * 2048 + d0);
      float f0 = bf2f(v.x), f1 = bf2f(v.y), f2 = bf2f(v.z), f3 = bf2f(v.w);
#pragma unroll
      for (int k = 0; k < 8; ++k) {
        int j = dir ? (m - 7 + k) : (m - k);
        if (j >= 0 && j < 4) {
          acc[k][0] = fmaf(wv[0][j], f0, acc[k][0]);
          acc[k][1] = fmaf(wv[1][j], f1, acc[k][1]);
          acc[k][2] = fmaf(wv[2][j], f2, acc[k][2]);
          acc[k][3] = fmaf(wv[3][j], f3, acc[k][3]);
        }
      }
    }
  }
#pragma unroll
  for (int k = 0; k < 8; ++k) {
    ushort4 o;
#pragma unroll
    for (int i = 0; i < 4; ++i) {
      float s = acc[k][i] * __builtin_amdgcn_rcpf(1.f + fexp2(-acc[k][i] * LOG2E_));
      ((unsigned short*)&o)[i] = f2bf(s);
    }
    *(ushort4*)(xsb + ((size_t)b * L_ + (t + k)) * DI_ + d0) = o;
  }
}

// ---------------------------------------------------------------------------
// Scan pass A: per (dir,b,d,chunk): E = local end state (fp16), dts = sum dt.
// dt is fp16; A-table precomputed.
// ---------------------------------------------------------------------------
__global__ __launch_bounds__(256) void scan_passA_k(
    const unsigned short* __restrict__ dtf, const unsigned short* __restrict__ dtr,
    const unsigned short* __restrict__ xsbf, const unsigned short* __restrict__ xsbr,
    const float* __restrict__ xdf, const float* __restrict__ xdr,
    const float* __restrict__ Atabf, const float* __restrict__ Atabr,
    unsigned short* __restrict__ E, float* __restrict__ dts)
{
  __shared__ float bS[CL_][16];         // B row per chunk step
  int bid  = blockIdx.x;               // [dir][b][c][dgrp]
  int dgrp = bid & 3;
  int c    = (bid >> 2) & (NC_ - 1);
  int b    = (bid >> 8) & 1;
  int dir  = bid >> 9;
  int d    = (dgrp << 8) + threadIdx.x;
  const unsigned short* dt = dir ? dtr : dtf;
  const unsigned short* xs = dir ? xsbr : xsbf;
  const float* xd = dir ? xdr : xdf;
  const float* At = dir ? Atabr : Atabf;
  if (threadIdx.x < CL_ * 4) {
    int li = threadIdx.x >> 2;
    int lc = threadIdx.x & 3;
    *(float4*)&bS[li][lc * 4] =
        *(const float4*)(xd + ((size_t)b * L_ + c * CL_ + li) * 64 + 32 + lc * 4);
  }
  float Ai2[16];
#pragma unroll
  for (int q = 0; q < 4; ++q) {
    float4 a4 = *(const float4*)(At + (size_t)d * 16 + q * 4);
    Ai2[4*q] = a4.x; Ai2[4*q+1] = a4.y; Ai2[4*q+2] = a4.z; Ai2[4*q+3] = a4.w;
  }
  float h[16];
#pragma unroll
  for (int s = 0; s < 16; ++s) h[s] = 0.f;
  int t0 = c * CL_ + (dir ? CL_ - 1 : 0);
  const long sdt = (dir ? -1L : 1L) * DI_;
  const unsigned short* dtp = dt + ((size_t)b * L_ + t0) * DI_ + d;
  const unsigned short* xsp = xs + ((size_t)b * L_ + t0) * DI_ + d;
  float dtsum = 0.f;
  __syncthreads();
#pragma unroll 2
  for (int i = 0; i < CL_; ++i) {
    int row = dir ? (CL_ - 1 - i) : i;
    float dtv = h2f(*dtp);
    float xv  = bf2f(*xsp);
    float Bv[16];
#pragma unroll
    for (int q = 0; q < 4; ++q) {
      float4 bq = *(const float4*)&bS[row][4 * q];
      Bv[4*q] = bq.x; Bv[4*q+1] = bq.y; Bv[4*q+2] = bq.z; Bv[4*q+3] = bq.w;
    }
    float dtx = dtv * xv;
    dtsum += dtv;
#pragma unroll
    for (int s = 0; s < 16; ++s) {
      float dA = fexp2(dtv * Ai2[s]);
      h[s] = fmaf(dA, h[s], dtx * Bv[s]);
    }
    dtp += sdt; xsp += sdt;
  }
  size_t base = ((((size_t)dir * B_ + b) * NC_ + c) * DI_ + d) * 16;
  unsigned pk[8];
#pragma unroll
  for (int q = 0; q < 8; ++q)
    pk[q] = (unsigned)f2h(h[2*q]) | ((unsigned)f2h(h[2*q+1]) << 16);
  *(uint4*)(E + base)     = make_uint4(pk[0], pk[1], pk[2], pk[3]);
  *(uint4*)(E + base + 8) = make_uint4(pk[4], pk[5], pk[6], pk[7]);
  dts[(((size_t)dir * B_ + b) * NC_ + c) * DI_ + d] = dtsum;
}

// ---------------------------------------------------------------------------
// Chunk prefix: Hin[c] = state entering chunk c (fp16 storage, fp32 chain).
// 8-wide batched loads hide L2/L3 latency across the serial fma chain.
// ---------------------------------------------------------------------------
__global__ __launch_bounds__(256) void scan_prefix_k(
    const unsigned short* __restrict__ E, const float* __restrict__ dts,
    const float* __restrict__ Atabf, const float* __restrict__ Atabr,
    unsigned short* __restrict__ Hin)
{
  int gid = blockIdx.x * 256 + threadIdx.x;   // [dir][b][d][s]
  int s   = gid & 15;
  int d   = (gid >> 4) & (DI_ - 1);
  int b   = (gid >> 14) & 1;
  int dir = gid >> 15;
  float Ai2 = (dir ? Atabr : Atabf)[(size_t)d * 16 + s];
  size_t eb  = (((size_t)dir * B_ + b) * NC_) * DI_ * 16 + (size_t)d * 16 + s;
  size_t db2 = (((size_t)dir * B_ + b) * NC_) * DI_ + d;
  const size_t es = (size_t)DI_ * 16;
  float h = 0.f;
  if (!dir) {
    size_t idx = eb;
    size_t di  = db2;
#pragma unroll 1
    for (int cb = 0; cb < NC_; cb += 8) {
      unsigned short Ev[8]; float dv[8];
#pragma unroll
      for (int k = 0; k < 8; ++k) {
        Ev[k] = E[idx + (size_t)k * es];
        dv[k] = dts[di + (size_t)k * DI_];
      }
#pragma unroll
      for (int k = 0; k < 8; ++k) {
        Hin[idx + (size_t)k * es] = f2h(h);
        h = fmaf(fexp2(dv[k] * Ai2), h, h2f(Ev[k]));
      }
      idx += 8 * es; di += 8 * (size_t)DI_;
    }
  } else {
    size_t idx = eb + (size_t)(NC_ - 1) * es;
    size_t di  = db2 + (size_t)(NC_ - 1) * DI_;
#pragma unroll 1
    for (int cb = 0; cb < NC_; cb += 8) {
      unsigned short Ev[8]; float dv[8];
#pragma unroll
      for (int k = 0; k < 8; ++k) {
        Ev[k] = E[idx - (size_t)k * es];
        dv[k] = dts[di - (size_t)k * DI_];
      }
#pragma unroll
      for (int k = 0; k < 8; ++k) {
        Hin[idx - (size_t)k * es] = f2h(h);
        h = fmaf(fexp2(dv[k] * Ai2), h, h2f(Ev[k]));
      }
      idx -= 8 * es; di -= 8 * (size_t)DI_;
    }
  }
}

// ---------------------------------------------------------------------------
// Scan pass C: replay chunk from Hin (fp16), y = (sum h*C + xs*Dp)*silu(z)
// dt is fp16; A-table precomputed.
// ---------------------------------------------------------------------------
__global__ __launch_bounds__(256) void scan_passC_k(
    const unsigned short* __restrict__ dtf, const unsigned short* __restrict__ dtr,
    const unsigned short* __restrict__ xsbf, const unsigned short* __restrict__ xsbr,
    const float* __restrict__ xdf, const float* __restrict__ xdr,
    const unsigned short* __restrict__ xzbf, const unsigned short* __restrict__ xzbr,
    const float* __restrict__ Atabf, const float* __restrict__ Atabr,
    const float* __restrict__ Dpf, const float* __restrict__ Dpr,
    const unsigned short* __restrict__ Hin,
    unsigned short* __restrict__ ybf, unsigned short* __restrict__ ybr)
{
  __shared__ float bcS[CL_][32];        // B(16)+C(16) per chunk step
  int bid  = blockIdx.x;
  int dgrp = bid & 3;
  int c    = (bid >> 2) & (NC_ - 1);
  int b    = (bid >> 8) & 1;
  int dir  = bid >> 9;
  int d    = (dgrp << 8) + threadIdx.x;
  const unsigned short* dt  = dir ? dtr : dtf;
  const unsigned short* xs = dir ? xsbr : xsbf;
  const float* xd  = dir ? xdr : xdf;
  const unsigned short* xz = dir ? xzbr : xzbf;
  const float* At  = dir ? Atabr : Atabf;
  unsigned short* yb = dir ? ybr : ybf;
  float Dpv = (dir ? Dpr : Dpf)[d];
  {
    int li = threadIdx.x >> 3;
    int lc = threadIdx.x & 7;
    *(float4*)&bcS[li][lc * 4] =
        *(const float4*)(xd + ((size_t)b * L_ + c * CL_ + li) * 64 + 32 + lc * 4);
  }
  float Ai2[16];
#pragma unroll
  for (int q = 0; q < 4; ++q) {
    float4 a4 = *(const float4*)(At + (size_t)d * 16 + q * 4);
    Ai2[4*q] = a4.x; Ai2[4*q+1] = a4.y; Ai2[4*q+2] = a4.z; Ai2[4*q+3] = a4.w;
  }
  size_t hb = ((((size_t)dir * B_ + b) * NC_ + c) * DI_ + d) * 16;
  float h[16];
  {
    uint4 ha = *(const uint4*)(Hin + hb);
    uint4 hbv = *(const uint4*)(Hin + hb + 8);
    unsigned hw[8] = {ha.x, ha.y, ha.z, ha.w, hbv.x, hbv.y, hbv.z, hbv.w};
#pragma unroll
    for (int q = 0; q < 8; ++q) {
      h[2*q]   = h2f((unsigned short)(hw[q] & 0xffffu));
      h[2*q+1] = h2f((unsigned short)(hw[q] >> 16));
    }
  }
  int t0 = c * CL_ + (dir ? CL_ - 1 : 0);
  const long sdt = (dir ? -1L : 1L) * DI_;
  const long sz_ = (dir ? -1L : 1L) * 2048;
  const unsigned short* dtp = dt + ((size_t)b * L_ + t0) * DI_ + d;
  const unsigned short* xsp = xs + ((size_t)b * L_ + t0) * DI_ + d;
  const unsigned short* zp = xz + ((size_t)b * L_ + t0) * 2048 + DI_ + d;
  unsigned short* ybp = yb + ((size_t)b * L_ + t0) * DI_ + d;
  __syncthreads();
#pragma unroll 2
  for (int i = 0; i < CL_; ++i) {
    int row = dir ? (CL_ - 1 - i) : i;
    float dtv = h2f(*dtp);
    float xv  = bf2f(*xsp);
    float z   = bf2f(*zp);
    float Bv[16], Cv[16];
#pragma unroll
    for (int q = 0; q < 4; ++q) {
      float4 bq = *(const float4*)&bcS[row][4 * q];
      float4 cq = *(const float4*)&bcS[row][16 + 4 * q];
      Bv[4*q] = bq.x; Bv[4*q+1] = bq.y; Bv[4*q+2] = bq.z; Bv[4*q+3] = bq.w;
      Cv[4*q] = cq.x; Cv[4*q+1] = cq.y; Cv[4*q+2] = cq.z; Cv[4*q+3] = cq.w;
    }
    float dtx = dtv * xv;
    float yacc = 0.f;
#pragma unroll
    for (int s = 0; s < 16; ++s) {
      float dA = fexp2(dtv * Ai2[s]);
      h[s] = fmaf(dA, h[s], dtx * Bv[s]);
      yacc = fmaf(h[s], Cv[s], yacc);
    }
    float yv = fmaf(xv, Dpv, yacc);
    float sz = z * __builtin_amdgcn_rcpf(1.f + fexp2(-z * LOG2E_));
    *ybp = f2bf(yv * sz);
    dtp += sdt; xsp += sdt; zp += sz_; ybp += sdt;
  }
}

// ---------------------------------------------------------------------------
extern "C" void kernel_launch(void* const* d_in, const int* in_sizes, int n_in,
                              void* d_out, int out_size, void* d_ws, size_t ws_size,
                              hipStream_t stream)
{
  const float* x       = (const float*)d_in[0];
  const float* Win_f   = (const float*)d_in[1];
  const float* convw_f = (const float*)d_in[2];
  const float* convb_f = (const float*)d_in[3];
  const float* Wx_f    = (const float*)d_in[4];
  const float* Wdt_f   = (const float*)d_in[5];
  const float* dtb_f   = (const float*)d_in[6];
  const float* Alog_f  = (const float*)d_in[7];
  const float* Dp_f    = (const float*)d_in[8];
  const float* Wout_f  = (const float*)d_in[9];
  const float* Win_r   = (const float*)d_in[10];
  const float* convw_r = (const float*)d_in[11];
  const float* convb_r = (const float*)d_in[12];
  const float* Wx_r    = (const float*)d_in[13];
  const float* Wdt_r   = (const float*)d_in[14];
  const float* dtb_r   = (const float*)d_in[15];
  const float* Alog_r  = (const float*)d_in[16];
  const float* Dp_r    = (const float*)d_in[17];
  const float* Wout_r  = (const float*)d_in[18];
  float* out = (float*)d_out;

  float* ws  = (float*)d_ws;
  float* xdf = ws;
  float* xdr = xdf + (size_t)M_ * 64;
  unsigned short* dtf = (unsigned short*)(xdr + (size_t)M_ * 64);   // fp16 dt
  unsigned short* dtr = dtf + (size_t)M_ * DI_;
  // E/Hin fp16 (8.4 MB each); fp16 part2 (8.4 MB) aliases Eh, dead before passA
  unsigned short* Eh = dtr + (size_t)M_ * DI_;
  unsigned short* Hh = Eh + (size_t)2 * B_ * NC_ * DI_ * 16;
  float* dtsb = (float*)(Hh + (size_t)2 * B_ * NC_ * DI_ * 16);
  unsigned short* part2 = Eh;
  unsigned short* xzbf    = (unsigned short*)(dtsb + (size_t)2 * B_ * NC_ * DI_);
  unsigned short* xzbr    = xzbf + (size_t)M_ * 2048;
  unsigned short* xb      = xzbr + (size_t)M_ * 2048;
  unsigned short* Winb_f  = xb + (size_t)M_ * DM_;
  unsigned short* Winb_r  = Winb_f + (size_t)2048 * DM_;
  unsigned short* Woutb_f = Winb_r + (size_t)2048 * DM_;
  unsigned short* Woutb_r = Woutb_f + (size_t)DM_ * DI_;
  unsigned short* ybf     = Woutb_r + (size_t)DM_ * DI_;
  unsigned short* ybr     = ybf + (size_t)M_ * DI_;
  unsigned short* xsbf    = ybr + (size_t)M_ * DI_;
  unsigned short* xsbr    = xsbf + (size_t)M_ * DI_;
  unsigned short* Wxb_f   = xsbr + (size_t)M_ * DI_;
  unsigned short* Wxb_r   = Wxb_f + (size_t)64 * DI_;
  unsigned short* Wdtb_f  = Wxb_r + (size_t)64 * DI_;
  unsigned short* Wdtb_r  = Wdtb_f + (size_t)DI_ * DTR_;
  unsigned short* drbf    = Wdtb_r + (size_t)DI_ * DTR_;
  unsigned short* drbr    = drbf + (size_t)M_ * DTR_;
  float* Atabf = (float*)(drbr + (size_t)M_ * DTR_);     // [d][s] fp32
  float* Atabr = Atabf + (size_t)DI_ * DS_;

  dim3 blk(256);

  // cast x, Win_f/r, Wout_f/r, Wx_f/r, Wdt_f/r to bf16; precompute Atab
  {
    CastArgs ca;
    ca.src[0] = x;      ca.dst[0] = xb;      ca.n[0] = M_ * DM_;
    ca.src[1] = Win_f;  ca.dst[1] = Winb_f;  ca.n[1] = 2048 * DM_;
    ca.src[2] = Win_r;  ca.dst[2] = Winb_r;  ca.n[2] = 2048 * DM_;
    ca.src[3] = Wout_f; ca.dst[3] = Woutb_f; ca.n[3] = DM_ * DI_;
    ca.src[4] = Wout_r; ca.dst[4] = Woutb_r; ca.n[4] = DM_ * DI_;
    ca.src[5] = Wx_f;   ca.dst[5] = Wxb_f;   ca.n[5] = 64 * DI_;
    ca.src[6] = Wx_r;   ca.dst[6] = Wxb_r;   ca.n[6] = 64 * DI_;
    ca.src[7] = Wdt_f;  ca.dst[7] = Wdtb_f;  ca.n[7] = DI_ * DTR_;
    ca.src[8] = Wdt_r;  ca.dst[8] = Wdtb_r;  ca.n[8] = DI_ * DTR_;
    int st = 0;
    for (int s = 0; s < 9; ++s) { ca.start[s] = st; st += ca.n[s]; }
    int total4 = st / 4;
    cast_multi_k<<<(total4 + 255) / 256, blk, 0, stream>>>(
        ca, total4, Alog_f, Alog_r, Atabf, Atabr);
  }

  // GEMM1 (bf16 MFMA, dirs fused, 3-buf counted-vmcnt pipeline)
  gemm1_mfma_k<<<dim3(2048 / 128, M_ / 128), blk, 0, stream>>>(
      xb, Winb_f, Winb_r, xzbf, xzbr);

  // conv + silu (both dirs, 8 timesteps/block), bf16 in/out
  conv_silu_k<<<2 * B_ * (L_ / 8), blk, 0, stream>>>(xzbf, xzbr, convw_f, convb_f,
      convw_r, convb_r, xsbf, xsbr);

  // GEMM2 (bf16 MFMA split-K, both dirs, fp16 partials) + reduce
  gemm2_mfma_k<<<dim3(KS_, M_ / 128, 2), blk, 0, stream>>>(
      xsbf, xsbr, Wxb_f, Wxb_r, part2);
  reduce_part_k<<<(2 * M_ * 16) / 256, blk, 0, stream>>>(part2, xdf, xdr,
      drbf, drbr);

  // GEMM3 (bf16 MFMA, both dirs): dt = softplus(dt_raw . Wdt^T + dtb) -> fp16
  gemm3_mfma_k<<<dim3(DI_ / 128, M_ / 128, 2), blk, 0, stream>>>(
      drbf, drbr, Wdtb_f, Wdtb_r, dtb_f, dtb_r, dtf, dtr);

  // chunked scan (A -> prefix -> C), P recomputed from dtsum
  scan_passA_k<<<2 * B_ * NC_ * 4, blk, 0, stream>>>(dtf, dtr, xsbf, xsbr,
      xdf, xdr, Atabf, Atabr, Eh, dtsb);
  scan_prefix_k<<<(2 * B_ * DI_ * 16) / 256, blk, 0, stream>>>(
      Eh, dtsb, Atabf, Atabr, Hh);
  scan_passC_k<<<2 * B_ * NC_ * 4, blk, 0, stream>>>(dtf, dtr, xsbf, xsbr,
      xdf, xdr, xzbf, xzbr, Atabf, Atabr, Dp_f, Dp_r, Hh, ybf, ybr);

  // GEMM4 fused (both dirs + add): out = y_f.Wout_f^T + y_r.Wout_r^T
  gemm4_fused_k<<<dim3(DM_ / 64, M_ / 128), dim3(512), 0, stream>>>(
      ybf, Woutb_f, ybr, Woutb_r, out);
}

// Round 11
// 245.149 us; speedup vs baseline: 1.0142x; 1.0064x over previous
//
#include <hip/hip_runtime.h>
#include <cmath>

#define B_   2
#define L_   2048
#define DM_  512
#define DI_  1024
#define DS_  16
#define DTR_ 32
#define M_   (B_*L_)   // 4096
#define NC_  64        // chunks
#define CL_  32        // chunk length (NC_*CL_ == L_)
#define KS_  8         // GEMM2 split-K factor
#define LOG2E_ 1.44269504088896340736f
#define LN2_   0.69314718055994530942f

typedef __attribute__((ext_vector_type(8))) short short8;   // 8 bf16 = 4 VGPRs
typedef __attribute__((ext_vector_type(4))) float floatx4;  // MFMA acc

__device__ inline unsigned short f2bf(float f) {
  unsigned u = __float_as_uint(f);
  unsigned r = (u + 0x7fffu + ((u >> 16) & 1u)) >> 16;   // RNE
  return (unsigned short)r;
}
__device__ inline float bf2f(unsigned short u) {
  return __uint_as_float(((unsigned)u) << 16);
}
// fp16 pack/unpack (v_cvt_f16_f32 / v_cvt_f32_f16)
__device__ inline unsigned short f2h(float f) {
  _Float16 h = (_Float16)f;
  return *(unsigned short*)&h;
}
__device__ inline float h2f(unsigned short u) {
  _Float16 h = *(_Float16*)&u;
  return (float)h;
}
// raw v_exp_f32 (2^x) / v_log_f32 (log2 x) — libm exp2f/log1pf are slow multi-inst paths
__device__ inline float fexp2(float x) { return __builtin_amdgcn_exp2f(x); }
__device__ inline float flog2(float x) { return __builtin_amdgcn_logf(x); }

__device__ inline void gload_lds16(const unsigned short* g, unsigned short* l) {
  __builtin_amdgcn_global_load_lds(
      (const __attribute__((address_space(1))) void*)g,
      (__attribute__((address_space(3))) void*)l, 16, 0, 0);
}

// ---------------------------------------------------------------------------
// GEMM1 (bf16 MFMA, BOTH dirs fused): xz_f = x.Win_f^T, xz_r = x.Win_r^T.
// 3-deep buffer rotation + counted vmcnt(6): measured -2us vs 2-buf (R10).
// LDS 3 x 24KB = 72KB -> still 2 blocks/CU.
// ---------------------------------------------------------------------------
__global__ __launch_bounds__(256, 2) void gemm1_mfma_k(
    const unsigned short* __restrict__ A,
    const unsigned short* __restrict__ Wf, const unsigned short* __restrict__ Wr,
    unsigned short* __restrict__ Cf, unsigned short* __restrict__ Cr)
{
  __shared__ unsigned short At[3][128 * 32];
  __shared__ unsigned short Wtf[3][128 * 32];
  __shared__ unsigned short Wtr[3][128 * 32];
  const int tid  = threadIdx.x;
  const int w    = tid >> 6;
  const int lane = tid & 63;
  const int wm   = w >> 1, wn = w & 1;
  const int row0 = blockIdx.y * 128, col0 = blockIdx.x * 128;
  const int lrow  = lane >> 2;
  const int lkoff = (lane & 3) * 8;
  const int fr = lane & 15;
  const int fq = (lane >> 4) * 8;
  const int K = DM_;           // 512
  const int NT = K >> 5;       // 16

  floatx4 accf[4][4], accr[4][4];
#pragma unroll
  for (int i = 0; i < 4; ++i)
#pragma unroll
    for (int j = 0; j < 4; ++j)
#pragma unroll
      for (int r = 0; r < 4; ++r) { accf[i][j][r] = 0.f; accr[i][j][r] = 0.f; }

  auto stage = [&](int buf, int k0) {   // 6 vmem instructions per wave
#pragma unroll
    for (int j = 0; j < 2; ++j) {
      int r = w * 32 + j * 16;
      gload_lds16(A  + (size_t)(row0 + r + lrow) * K + k0 + lkoff, At[buf]  + r * 32);
      gload_lds16(Wf + (size_t)(col0 + r + lrow) * K + k0 + lkoff, Wtf[buf] + r * 32);
      gload_lds16(Wr + (size_t)(col0 + r + lrow) * K + k0 + lkoff, Wtr[buf] + r * 32);
    }
  };
  auto compute = [&](int buf) {
    short8 af[4], bff[4], bfr[4];
#pragma unroll
    for (int i = 0; i < 4; ++i) {
      af[i]  = *(const short8*)&At[buf][(64 * wm + 16 * i + fr) * 32 + fq];
      bff[i] = *(const short8*)&Wtf[buf][(64 * wn + 16 * i + fr) * 32 + fq];
      bfr[i] = *(const short8*)&Wtr[buf][(64 * wn + 16 * i + fr) * 32 + fq];
    }
#pragma unroll
    for (int i = 0; i < 4; ++i)
#pragma unroll
      for (int j = 0; j < 4; ++j) {
        accf[i][j] = __builtin_amdgcn_mfma_f32_16x16x32_bf16(af[i], bff[j], accf[i][j], 0, 0, 0);
        accr[i][j] = __builtin_amdgcn_mfma_f32_16x16x32_bf16(af[i], bfr[j], accr[i][j], 0, 0, 0);
      }
  };

  // prologue: two stages in flight; retire the first (keep 6 outstanding)
  stage(0, 0);
  stage(1, 32);
  asm volatile("s_waitcnt vmcnt(6)" ::: "memory");
  __builtin_amdgcn_s_barrier();
  __builtin_amdgcn_sched_barrier(0);
  // steady state: issue stage(t+2), compute(t), retire stage(t+1)'s loads
#pragma unroll 1
  for (int t = 0; t < NT - 2; ++t) {
    stage((t + 2) % 3, (t + 2) << 5);
    compute(t % 3);
    asm volatile("s_waitcnt vmcnt(6)" ::: "memory");
    __builtin_amdgcn_s_barrier();
    __builtin_amdgcn_sched_barrier(0);
  }
  // tail: t = NT-2 (no new stage; drain last stage), then t = NT-1
  compute((NT - 2) % 3);
  asm volatile("s_waitcnt vmcnt(0)" ::: "memory");
  __builtin_amdgcn_s_barrier();
  __builtin_amdgcn_sched_barrier(0);
  compute((NT - 1) % 3);

#pragma unroll
  for (int i = 0; i < 4; ++i) {
    int rg = row0 + 64 * wm + 16 * i + ((lane >> 4) << 2);
#pragma unroll
    for (int j = 0; j < 4; ++j) {
      int cg = col0 + 64 * wn + 16 * j + (lane & 15);
#pragma unroll
      for (int r = 0; r < 4; ++r) {
        Cf[(size_t)(rg + r) * 2048 + cg] = f2bf(accf[i][j][r]);
        Cr[(size_t)(rg + r) * 2048 + cg] = f2bf(accr[i][j][r]);
      }
    }
  }
}

// ---------------------------------------------------------------------------
// GEMM4 fused (bf16 MFMA): out = y_f . Wout_f^T + y_r . Wout_r^T  (fp32 out)
// 128x64 tile, 8 waves. Runs 1 block/CU (grid 256) -> NO co-resident block to
// hide the barrier drain -> 3-deep rotation + counted vmcnt(3) (3 vmem/wave
// per stage; steady state 6 outstanding, retire oldest 3). LDS 72KB.
// Per-output K-order identical -> bitwise-identical result.
// ---------------------------------------------------------------------------
__global__ __launch_bounds__(512, 2) void gemm4_fused_k(
    const unsigned short* __restrict__ ybf, const unsigned short* __restrict__ Woutbf,
    const unsigned short* __restrict__ ybr, const unsigned short* __restrict__ Woutbr,
    float* __restrict__ out)
{
  __shared__ unsigned short At[3][2][128 * 32];   // [buf][khalf] 8KB each
  __shared__ unsigned short Wt[3][2][64 * 32];    // [buf][khalf] 4KB each
  const int tid  = threadIdx.x;
  const int w    = tid >> 6;          // 0..7
  const int lane = tid & 63;
  const int col0 = blockIdx.x * 64;
  const int row0 = blockIdx.y * 128;
  const int lrow  = lane >> 2;
  const int lkoff = (lane & 3) * 8;
  const int fr = lane & 15;
  const int fq = (lane >> 4) * 8;
  const int NT = 32;   // 2 sources x 16 K-tiles of 64

  floatx4 acc[4];
#pragma unroll
  for (int j = 0; j < 4; ++j)
#pragma unroll
    for (int r = 0; r < 4; ++r) acc[j][r] = 0.f;

  // t in [0,32): src = t>>4, k0 = (t&15)*64. 3 vmem per wave.
  auto stage = [&](int buf, int t) {
    const unsigned short* A = (t & 16) ? ybr : ybf;
    const unsigned short* W = (t & 16) ? Woutbr : Woutbf;
    const int k0 = (t & 15) << 6;
#pragma unroll
    for (int h = 0; h < 2; ++h) {
      gload_lds16(A + (size_t)(row0 + 16 * w + lrow) * DI_ + k0 + 32 * h + lkoff,
                  At[buf][h] + (16 * w) * 32);
    }
    {
      int h = w >> 2;
      int r = (w & 3) * 16;
      gload_lds16(W + (size_t)(col0 + r + lrow) * DI_ + k0 + 32 * h + lkoff,
                  Wt[buf][h] + r * 32);
    }
  };
  auto compute = [&](int buf) {
    short8 af[2], bf[2][4];
#pragma unroll
    for (int h = 0; h < 2; ++h) {
      af[h] = *(const short8*)&At[buf][h][(16 * w + fr) * 32 + fq];
#pragma unroll
      for (int j = 0; j < 4; ++j)
        bf[h][j] = *(const short8*)&Wt[buf][h][(16 * j + fr) * 32 + fq];
    }
#pragma unroll
    for (int h = 0; h < 2; ++h)
#pragma unroll
      for (int j = 0; j < 4; ++j)
        acc[j] = __builtin_amdgcn_mfma_f32_16x16x32_bf16(af[h], bf[h][j], acc[j], 0, 0, 0);
  };

  // prologue: two stages in flight; retire the first (keep 3 outstanding)
  stage(0, 0);
  stage(1, 1);
  asm volatile("s_waitcnt vmcnt(3)" ::: "memory");
  __builtin_amdgcn_s_barrier();
  __builtin_amdgcn_sched_barrier(0);
#pragma unroll 1
  for (int t = 0; t < NT - 2; ++t) {
    stage((t + 2) % 3, t + 2);
    compute(t % 3);
    asm volatile("s_waitcnt vmcnt(3)" ::: "memory");
    __builtin_amdgcn_s_barrier();
    __builtin_amdgcn_sched_barrier(0);
  }
  compute((NT - 2) % 3);
  asm volatile("s_waitcnt vmcnt(0)" ::: "memory");
  __builtin_amdgcn_s_barrier();
  __builtin_amdgcn_sched_barrier(0);
  compute((NT - 1) % 3);

  const int rg = row0 + 16 * w + ((lane >> 4) << 2);
#pragma unroll
  for (int j = 0; j < 4; ++j) {
    int cg = col0 + 16 * j + (lane & 15);
#pragma unroll
    for (int r = 0; r < 4; ++r)
      out[(size_t)(rg + r) * DM_ + cg] = acc[j][r];
  }
}

// ---------------------------------------------------------------------------
// GEMM2 (bf16 MFMA, split-K, both dirs): part[dir][ks][m][n] in FP16.
// Single-barrier double-buffered pipeline.
// ---------------------------------------------------------------------------
__global__ __launch_bounds__(256) void gemm2_mfma_k(
    const unsigned short* __restrict__ xsbf, const unsigned short* __restrict__ xsbr,
    const unsigned short* __restrict__ Wxbf, const unsigned short* __restrict__ Wxbr,
    unsigned short* __restrict__ part)
{
  __shared__ unsigned short At[2][128 * 32];
  __shared__ unsigned short Wt[2][64 * 32];
  const int tid  = threadIdx.x;
  const int w    = tid >> 6;
  const int lane = tid & 63;
  const int ks   = blockIdx.x;
  const int row0 = blockIdx.y * 128;
  const int dir  = blockIdx.z;
  const unsigned short* A = dir ? xsbr : xsbf;
  const unsigned short* W = dir ? Wxbr : Wxbf;
  const int kbase = ks * (DI_ / KS_);
  const int lrow  = lane >> 2;
  const int lkoff = (lane & 3) * 8;
  const int fr = lane & 15;
  const int fq = (lane >> 4) * 8;

  floatx4 acc[2][4];
#pragma unroll
  for (int i = 0; i < 2; ++i)
#pragma unroll
    for (int j = 0; j < 4; ++j)
#pragma unroll
      for (int r = 0; r < 4; ++r) acc[i][j][r] = 0.f;

  auto stage = [&](int buf, int k0) {
#pragma unroll
    for (int j = 0; j < 2; ++j) {
      int r = w * 32 + j * 16;
      gload_lds16(A + (size_t)(row0 + r + lrow) * DI_ + kbase + k0 + lkoff, At[buf] + r * 32);
    }
    int r = w * 16;
    gload_lds16(W + (size_t)(r + lrow) * DI_ + kbase + k0 + lkoff, Wt[buf] + r * 32);
  };
  auto compute = [&](int buf) {
    short8 af[2], bf[4];
#pragma unroll
    for (int i = 0; i < 2; ++i)
      af[i] = *(const short8*)&At[buf][(32 * w + 16 * i + fr) * 32 + fq];
#pragma unroll
    for (int j = 0; j < 4; ++j)
      bf[j] = *(const short8*)&Wt[buf][(16 * j + fr) * 32 + fq];
#pragma unroll
    for (int i = 0; i < 2; ++i)
#pragma unroll
      for (int j = 0; j < 4; ++j)
        acc[i][j] = __builtin_amdgcn_mfma_f32_16x16x32_bf16(af[i], bf[j], acc[i][j], 0, 0, 0);
  };

  const int NT = (DI_ / KS_) >> 5;   // 4
  stage(0, 0);
  __syncthreads();
  int cur = 0;
  for (int t = 0; t < NT - 1; ++t) {
    stage(cur ^ 1, (t + 1) << 5);
    compute(cur);
    __syncthreads();
    cur ^= 1;
  }
  compute(cur);

  unsigned short* dst = part + (((size_t)dir * KS_ + ks) * M_) * 64;
#pragma unroll
  for (int i = 0; i < 2; ++i) {
    int rg = row0 + 32 * w + 16 * i + ((lane >> 4) << 2);
#pragma unroll
    for (int j = 0; j < 4; ++j) {
      int cg = 16 * j + (lane & 15);
#pragma unroll
      for (int r = 0; r < 4; ++r)
        dst[(size_t)(rg + r) * 64 + cg] = f2h(acc[i][j][r]);
    }
  }
}

// Reduce split-K fp16 partials: xd[dir][m][n] = sum_ks part[dir][ks][m][n].
// Also emits dt_raw (cols 0..31) as bf16 for the MFMA GEMM3.
__global__ __launch_bounds__(256) void reduce_part_k(
    const unsigned short* __restrict__ part, float* __restrict__ xdf, float* __restrict__ xdr,
    unsigned short* __restrict__ drbf, unsigned short* __restrict__ drbr)
{
  int g = blockIdx.x * 256 + threadIdx.x;
  int n4  = g & 15;
  int m   = (g >> 4) & (M_ - 1);
  int dir = g >> 16;
  const unsigned short* p = part + ((size_t)dir * KS_ * M_ + m) * 64 + n4 * 4;
  float4 s = make_float4(0.f, 0.f, 0.f, 0.f);
#pragma unroll
  for (int ks = 0; ks < KS_; ++ks) {
    ushort4 v = *(const ushort4*)(p + (size_t)ks * M_ * 64);
    s.x += h2f(v.x); s.y += h2f(v.y); s.z += h2f(v.z); s.w += h2f(v.w);
  }
  float* xd = dir ? xdr : xdf;
  *(float4*)(xd + (size_t)m * 64 + n4 * 4) = s;
  if (n4 < 8) {   // dt_raw columns 0..31 -> bf16
    unsigned short* dr = dir ? drbr : drbf;
    ushort4 o;
    o.x = f2bf(s.x); o.y = f2bf(s.y); o.z = f2bf(s.z); o.w = f2bf(s.w);
    *(ushort4*)(dr + (size_t)m * 32 + n4 * 4) = o;
  }
}

// ---------------------------------------------------------------------------
// Fused fp32 -> bf16 cast of 9 tensors + Atab precompute:
// Atab[dir][d][s] = -exp(Alog[d][s]) * log2(e)   (used by all scan kernels)
// ---------------------------------------------------------------------------
struct CastArgs {
  const float* src[9];
  unsigned short* dst[9];
  int start[9];
  int n[9];
};

__global__ __launch_bounds__(256) void cast_multi_k(
    CastArgs a, int total4,
    const float* __restrict__ Alf, const float* __restrict__ Alr,
    float* __restrict__ Atf, float* __restrict__ Atr)
{
  int g = blockIdx.x * 256 + threadIdx.x;
  if (g >= total4) return;
  if (g < 8192) {   // 2 * 1024 * 16 / 4 float4's of Atab
    const float* Al = (g < 4096) ? Alf : Alr;
    float* At = (g < 4096) ? Atf : Atr;
    int off = (g & 4095) * 4;
    float4 v = *(const float4*)(Al + off);
    float4 o = make_float4(-__expf(v.x) * LOG2E_, -__expf(v.y) * LOG2E_,
                           -__expf(v.z) * LOG2E_, -__expf(v.w) * LOG2E_);
    *(float4*)(At + off) = o;
  }
  int e = g * 4;
#pragma unroll 1
  for (int s = 0; s < 9; ++s) {
    if (e < a.start[s] + a.n[s]) {
      int off = e - a.start[s];
      float4 v = *(const float4*)(a.src[s] + off);
      ushort4 o;
      o.x = f2bf(v.x); o.y = f2bf(v.y); o.z = f2bf(v.z); o.w = f2bf(v.w);
      *(ushort4*)(a.dst[s] + off) = o;
      return;
    }
  }
}

// ---------------------------------------------------------------------------
// GEMM3 (bf16 MFMA, both dirs via grid.z): dt = softplus(dt_raw . Wdt^T + dtb)
// K=32 == one 16x16x32 MFMA. 128x128 tile, 4 waves x (4x4) tiles, one K-step.
// OUTPUT fp16 (dt feeds exp2(dt*A); 2^-11 relative error is harmless).
// ---------------------------------------------------------------------------
__global__ __launch_bounds__(256) void gemm3_mfma_k(
    const unsigned short* __restrict__ drbf, const unsigned short* __restrict__ drbr,
    const unsigned short* __restrict__ Wdtbf, const unsigned short* __restrict__ Wdtbr,
    const float* __restrict__ b0, const float* __restrict__ b1,
    unsigned short* __restrict__ C0, unsigned short* __restrict__ C1)
{
  __shared__ unsigned short At[128 * 32];
  __shared__ unsigned short Wt[128 * 32];
  const unsigned short* A = blockIdx.z ? drbr : drbf;
  const unsigned short* W = blockIdx.z ? Wdtbr : Wdtbf;
  const float* bias = blockIdx.z ? b1 : b0;
  unsigned short* C = blockIdx.z ? C1 : C0;
  const int tid  = threadIdx.x;
  const int w    = tid >> 6;
  const int lane = tid & 63;
  const int wm   = w >> 1, wn = w & 1;
  const int row0 = blockIdx.y * 128, col0 = blockIdx.x * 128;
  const int lrow  = lane >> 2;
  const int lkoff = (lane & 3) * 8;
  const int fr = lane & 15;
  const int fq = (lane >> 4) * 8;

#pragma unroll
  for (int j = 0; j < 2; ++j) {
    int r = w * 32 + j * 16;
    gload_lds16(A + (size_t)(row0 + r + lrow) * DTR_ + lkoff, At + r * 32);
    gload_lds16(W + (size_t)(col0 + r + lrow) * DTR_ + lkoff, Wt + r * 32);
  }
  __syncthreads();
  short8 af[4], bf[4];
#pragma unroll
  for (int i = 0; i < 4; ++i) {
    af[i] = *(const short8*)&At[(64 * wm + 16 * i + fr) * 32 + fq];
    bf[i] = *(const short8*)&Wt[(64 * wn + 16 * i + fr) * 32 + fq];
  }
  floatx4 acc[4][4];
#pragma unroll
  for (int i = 0; i < 4; ++i)
#pragma unroll
    for (int j = 0; j < 4; ++j) {
#pragma unroll
      for (int r = 0; r < 4; ++r) acc[i][j][r] = 0.f;
      acc[i][j] = __builtin_amdgcn_mfma_f32_16x16x32_bf16(af[i], bf[j], acc[i][j], 0, 0, 0);
    }
#pragma unroll
  for (int i = 0; i < 4; ++i) {
    int rg = row0 + 64 * wm + 16 * i + ((lane >> 4) << 2);
#pragma unroll
    for (int j = 0; j < 4; ++j) {
      int cg = col0 + 64 * wn + 16 * j + (lane & 15);
      float bv = bias[cg];
#pragma unroll
      for (int r = 0; r < 4; ++r) {
        float v = acc[i][j][r] + bv;
        float e = fexp2(-fabsf(v) * LOG2E_);
        float sp = fmaxf(v, 0.f) + LN2_ * flog2(1.f + e);
        C[(size_t)(rg + r) * DI_ + cg] = f2h(sp);
      }
    }
  }
}

// ---------------------------------------------------------------------------
// Depthwise conv(4) + bias + SiLU, both directions; bf16 in (xz) / bf16 out.
// EIGHT timesteps per block: 11 input rows feed 8 outputs, weights loaded once.
// Per-output tap order (j ascending) preserved -> bitwise identical.
// ---------------------------------------------------------------------------
__global__ __launch_bounds__(256) void conv_silu_k(
    const unsigned short* __restrict__ xzbf, const unsigned short* __restrict__ xzbr,
    const float* __restrict__ cwf, const float* __restrict__ cbf,
    const float* __restrict__ cwr, const float* __restrict__ cbr,
    unsigned short* __restrict__ xsbf, unsigned short* __restrict__ xsbr)
{
  int bid = blockIdx.x;                 // [dir][b][t>>3]
  int tg  = bid & (L_ / 8 - 1);
  int b   = (bid >> 8) & (B_ - 1);
  int dir = bid >> 9;
  int t   = tg << 3;
  const unsigned short* xz = dir ? xzbr : xzbf;
  const float* cw = dir ? cwr : cwf;
  const float* cb = dir ? cbr : cbf;
  unsigned short* xsb = dir ? xsbr : xsbf;
  int d0 = threadIdx.x << 2;
  float wv[4][4];
#pragma unroll
  for (int i = 0; i < 4; ++i) {
    float4 w4 = *(const float4*)(cw + (size_t)(d0 + i) * 4);
    wv[i][0] = w4.x; wv[i][1] = w4.y; wv[i][2] = w4.z; wv[i][3] = w4.w;
  }
  float4 cbv = *(const float4*)(cb + d0);
  float acc[8][4];   // [k = output t+k][i = channel]
#pragma unroll
  for (int k = 0; k < 8; ++k) {
    acc[k][0] = cbv.x; acc[k][1] = cbv.y; acc[k][2] = cbv.z; acc[k][3] = cbv.w;
  }
#pragma unroll
  for (int m = 0; m < 11; ++m) {
    int tt = dir ? (t + 10 - m) : (t - 3 + m);
    if (tt >= 0 && tt < L_) {
      ushort4 v = *(const ushort4*)(xz + ((size_t)b * L_ + tt) * 2048 + d0);
      float f0 = bf2f(v.x), f1 = bf2f(v.y), f2 = bf2f(v.z), f3 = bf2f(v.w);
#pragma unroll
      for (int k = 0; k < 8; ++k) {
        int j = dir ? (m - 7 + k) : (m - k);
        if (j >= 0 && j < 4) {
          acc[k][0] = fmaf(wv[0][j], f0, acc[k][0]);
          acc[k][1] = fmaf(wv[1][j], f1, acc[k][1]);
          acc[k][2] = fmaf(wv[2][j], f2, acc[k][2]);
          acc[k][3] = fmaf(wv[3][j], f3, acc[k][3]);
        }
      }
    }
  }
#pragma unroll
  for (int k = 0; k < 8; ++k) {
    ushort4 o;
#pragma unroll
    for (int i = 0; i < 4; ++i) {
      float s = acc[k][i] * __builtin_amdgcn_rcpf(1.f + fexp2(-acc[k][i] * LOG2E_));
      ((unsigned short*)&o)[i] = f2bf(s);
    }
    *(ushort4*)(xsb + ((size_t)b * L_ + (t + k)) * DI_ + d0) = o;
  }
}

// ---------------------------------------------------------------------------
// Scan pass A: per (dir,b,d,chunk): E = local end state (fp16), dts = sum dt.
// dt is fp16; A-table precomputed.
// ---------------------------------------------------------------------------
__global__ __launch_bounds__(256) void scan_passA_k(
    const unsigned short* __restrict__ dtf, const unsigned short* __restrict__ dtr,
    const unsigned short* __restrict__ xsbf, const unsigned short* __restrict__ xsbr,
    const float* __restrict__ xdf, const float* __restrict__ xdr,
    const float* __restrict__ Atabf, const float* __restrict__ Atabr,
    unsigned short* __restrict__ E, float* __restrict__ dts)
{
  __shared__ float bS[CL_][16];         // B row per chunk step
  int bid  = blockIdx.x;               // [dir][b][c][dgrp]
  int dgrp = bid & 3;
  int c    = (bid >> 2) & (NC_ - 1);
  int b    = (bid >> 8) & 1;
  int dir  = bid >> 9;
  int d    = (dgrp << 8) + threadIdx.x;
  const unsigned short* dt = dir ? dtr : dtf;
  const unsigned short* xs = dir ? xsbr : xsbf;
  const float* xd = dir ? xdr : xdf;
  const float* At = dir ? Atabr : Atabf;
  if (threadIdx.x < CL_ * 4) {
    int li = threadIdx.x >> 2;
    int lc = threadIdx.x & 3;
    *(float4*)&bS[li][lc * 4] =
        *(const float4*)(xd + ((size_t)b * L_ + c * CL_ + li) * 64 + 32 + lc * 4);
  }
  float Ai2[16];
#pragma unroll
  for (int q = 0; q < 4; ++q) {
    float4 a4 = *(const float4*)(At + (size_t)d * 16 + q * 4);
    Ai2[4*q] = a4.x; Ai2[4*q+1] = a4.y; Ai2[4*q+2] = a4.z; Ai2[4*q+3] = a4.w;
  }
  float h[16];
#pragma unroll
  for (int s = 0; s < 16; ++s) h[s] = 0.f;
  int t0 = c * CL_ + (dir ? CL_ - 1 : 0);
  const long sdt = (dir ? -1L : 1L) * DI_;
  const unsigned short* dtp = dt + ((size_t)b * L_ + t0) * DI_ + d;
  const unsigned short* xsp = xs + ((size_t)b * L_ + t0) * DI_ + d;
  float dtsum = 0.f;
  __syncthreads();
#pragma unroll 2
  for (int i = 0; i < CL_; ++i) {
    int row = dir ? (CL_ - 1 - i) : i;
    float dtv = h2f(*dtp);
    float xv  = bf2f(*xsp);
    float Bv[16];
#pragma unroll
    for (int q = 0; q < 4; ++q) {
      float4 bq = *(const float4*)&bS[row][4 * q];
      Bv[4*q] = bq.x; Bv[4*q+1] = bq.y; Bv[4*q+2] = bq.z; Bv[4*q+3] = bq.w;
    }
    float dtx = dtv * xv;
    dtsum += dtv;
#pragma unroll
    for (int s = 0; s < 16; ++s) {
      float dA = fexp2(dtv * Ai2[s]);
      h[s] = fmaf(dA, h[s], dtx * Bv[s]);
    }
    dtp += sdt; xsp += sdt;
  }
  size_t base = ((((size_t)dir * B_ + b) * NC_ + c) * DI_ + d) * 16;
  unsigned pk[8];
#pragma unroll
  for (int q = 0; q < 8; ++q)
    pk[q] = (unsigned)f2h(h[2*q]) | ((unsigned)f2h(h[2*q+1]) << 16);
  *(uint4*)(E + base)     = make_uint4(pk[0], pk[1], pk[2], pk[3]);
  *(uint4*)(E + base + 8) = make_uint4(pk[4], pk[5], pk[6], pk[7]);
  dts[(((size_t)dir * B_ + b) * NC_ + c) * DI_ + d] = dtsum;
}

// ---------------------------------------------------------------------------
// Chunk prefix: Hin[c] = state entering chunk c (fp16 storage, fp32 chain).
// 8-wide batched loads hide L2/L3 latency across the serial fma chain.
// ---------------------------------------------------------------------------
__global__ __launch_bounds__(256) void scan_prefix_k(
    const unsigned short* __restrict__ E, const float* __restrict__ dts,
    const float* __restrict__ Atabf, const float* __restrict__ Atabr,
    unsigned short* __restrict__ Hin)
{
  int gid = blockIdx.x * 256 + threadIdx.x;   // [dir][b][d][s]
  int s   = gid & 15;
  int d   = (gid >> 4) & (DI_ - 1);
  int b   = (gid >> 14) & 1;
  int dir = gid >> 15;
  float Ai2 = (dir ? Atabr : Atabf)[(size_t)d * 16 + s];
  size_t eb  = (((size_t)dir * B_ + b) * NC_) * DI_ * 16 + (size_t)d * 16 + s;
  size_t db2 = (((size_t)dir * B_ + b) * NC_) * DI_ + d;
  const size_t es = (size_t)DI_ * 16;
  float h = 0.f;
  if (!dir) {
    size_t idx = eb;
    size_t di  = db2;
#pragma unroll 1
    for (int cb = 0; cb < NC_; cb += 8) {
      unsigned short Ev[8]; float dv[8];
#pragma unroll
      for (int k = 0; k < 8; ++k) {
        Ev[k] = E[idx + (size_t)k * es];
        dv[k] = dts[di + (size_t)k * DI_];
      }
#pragma unroll
      for (int k = 0; k < 8; ++k) {
        Hin[idx + (size_t)k * es] = f2h(h);
        h = fmaf(fexp2(dv[k] * Ai2), h, h2f(Ev[k]));
      }
      idx += 8 * es; di += 8 * (size_t)DI_;
    }
  } else {
    size_t idx = eb + (size_t)(NC_ - 1) * es;
    size_t di  = db2 + (size_t)(NC_ - 1) * DI_;
#pragma unroll 1
    for (int cb = 0; cb < NC_; cb += 8) {
      unsigned short Ev[8]; float dv[8];
#pragma unroll
      for (int k = 0; k < 8; ++k) {
        Ev[k] = E[idx - (size_t)k * es];
        dv[k] = dts[di - (size_t)k * DI_];
      }
#pragma unroll
      for (int k = 0; k < 8; ++k) {
        Hin[idx - (size_t)k * es] = f2h(h);
        h = fmaf(fexp2(dv[k] * Ai2), h, h2f(Ev[k]));
      }
      idx -= 8 * es; di -= 8 * (size_t)DI_;
    }
  }
}

// ---------------------------------------------------------------------------
// Scan pass C: replay chunk from Hin (fp16), y = (sum h*C + xs*Dp)*silu(z)
// dt is fp16; A-table precomputed.
// ---------------------------------------------------------------------------
__global__ __launch_bounds__(256) void scan_passC_k(
    const unsigned short* __restrict__ dtf, const unsigned short* __restrict__ dtr,
    const unsigned short* __restrict__ xsbf, const unsigned short* __restrict__ xsbr,
    const float* __restrict__ xdf, const float* __restrict__ xdr,
    const unsigned short* __restrict__ xzbf, const unsigned short* __restrict__ xzbr,
    const float* __restrict__ Atabf, const float* __restrict__ Atabr,
    const float* __restrict__ Dpf, const float* __restrict__ Dpr,
    const unsigned short* __restrict__ Hin,
    unsigned short* __restrict__ ybf, unsigned short* __restrict__ ybr)
{
  __shared__ float bcS[CL_][32];        // B(16)+C(16) per chunk step
  int bid  = blockIdx.x;
  int dgrp = bid & 3;
  int c    = (bid >> 2) & (NC_ - 1);
  int b    = (bid >> 8) & 1;
  int dir  = bid >> 9;
  int d    = (dgrp << 8) + threadIdx.x;
  const unsigned short* dt  = dir ? dtr : dtf;
  const unsigned short* xs = dir ? xsbr : xsbf;
  const float* xd  = dir ? xdr : xdf;
  const unsigned short* xz = dir ? xzbr : xzbf;
  const float* At  = dir ? Atabr : Atabf;
  unsigned short* yb = dir ? ybr : ybf;
  float Dpv = (dir ? Dpr : Dpf)[d];
  {
    int li = threadIdx.x >> 3;
    int lc = threadIdx.x & 7;
    *(float4*)&bcS[li][lc * 4] =
        *(const float4*)(xd + ((size_t)b * L_ + c * CL_ + li) * 64 + 32 + lc * 4);
  }
  float Ai2[16];
#pragma unroll
  for (int q = 0; q < 4; ++q) {
    float4 a4 = *(const float4*)(At + (size_t)d * 16 + q * 4);
    Ai2[4*q] = a4.x; Ai2[4*q+1] = a4.y; Ai2[4*q+2] = a4.z; Ai2[4*q+3] = a4.w;
  }
  size_t hb = ((((size_t)dir * B_ + b) * NC_ + c) * DI_ + d) * 16;
  float h[16];
  {
    uint4 ha = *(const uint4*)(Hin + hb);
    uint4 hbv = *(const uint4*)(Hin + hb + 8);
    unsigned hw[8] = {ha.x, ha.y, ha.z, ha.w, hbv.x, hbv.y, hbv.z, hbv.w};
#pragma unroll
    for (int q = 0; q < 8; ++q) {
      h[2*q]   = h2f((unsigned short)(hw[q] & 0xffffu));
      h[2*q+1] = h2f((unsigned short)(hw[q] >> 16));
    }
  }
  int t0 = c * CL_ + (dir ? CL_ - 1 : 0);
  const long sdt = (dir ? -1L : 1L) * DI_;
  const long sz_ = (dir ? -1L : 1L) * 2048;
  const unsigned short* dtp = dt + ((size_t)b * L_ + t0) * DI_ + d;
  const unsigned short* xsp = xs + ((size_t)b * L_ + t0) * DI_ + d;
  const unsigned short* zp = xz + ((size_t)b * L_ + t0) * 2048 + DI_ + d;
  unsigned short* ybp = yb + ((size_t)b * L_ + t0) * DI_ + d;
  __syncthreads();
#pragma unroll 2
  for (int i = 0; i < CL_; ++i) {
    int row = dir ? (CL_ - 1 - i) : i;
    float dtv = h2f(*dtp);
    float xv  = bf2f(*xsp);
    float z   = bf2f(*zp);
    float Bv[16], Cv[16];
#pragma unroll
    for (int q = 0; q < 4; ++q) {
      float4 bq = *(const float4*)&bcS[row][4 * q];
      float4 cq = *(const float4*)&bcS[row][16 + 4 * q];
      Bv[4*q] = bq.x; Bv[4*q+1] = bq.y; Bv[4*q+2] = bq.z; Bv[4*q+3] = bq.w;
      Cv[4*q] = cq.x; Cv[4*q+1] = cq.y; Cv[4*q+2] = cq.z; Cv[4*q+3] = cq.w;
    }
    float dtx = dtv * xv;
    float yacc = 0.f;
#pragma unroll
    for (int s = 0; s < 16; ++s) {
      float dA = fexp2(dtv * Ai2[s]);
      h[s] = fmaf(dA, h[s], dtx * Bv[s]);
      yacc = fmaf(h[s], Cv[s], yacc);
    }
    float yv = fmaf(xv, Dpv, yacc);
    float sz = z * __builtin_amdgcn_rcpf(1.f + fexp2(-z * LOG2E_));
    *ybp = f2bf(yv * sz);
    dtp += sdt; xsp += sdt; zp += sz_; ybp += sdt;
  }
}

// ---------------------------------------------------------------------------
extern "C" void kernel_launch(void* const* d_in, const int* in_sizes, int n_in,
                              void* d_out, int out_size, void* d_ws, size_t ws_size,
                              hipStream_t stream)
{
  const float* x       = (const float*)d_in[0];
  const float* Win_f   = (const float*)d_in[1];
  const float* convw_f = (const float*)d_in[2];
  const float* convb_f = (const float*)d_in[3];
  const float* Wx_f    = (const float*)d_in[4];
  const float* Wdt_f   = (const float*)d_in[5];
  const float* dtb_f   = (const float*)d_in[6];
  const float* Alog_f  = (const float*)d_in[7];
  const float* Dp_f    = (const float*)d_in[8];
  const float* Wout_f  = (const float*)d_in[9];
  const float* Win_r   = (const float*)d_in[10];
  const float* convw_r = (const float*)d_in[11];
  const float* convb_r = (const float*)d_in[12];
  const float* Wx_r    = (const float*)d_in[13];
  const float* Wdt_r   = (const float*)d_in[14];
  const float* dtb_r   = (const float*)d_in[15];
  const float* Alog_r  = (const float*)d_in[16];
  const float* Dp_r    = (const float*)d_in[17];
  const float* Wout_r  = (const float*)d_in[18];
  float* out = (float*)d_out;

  float* ws  = (float*)d_ws;
  float* xdf = ws;
  float* xdr = xdf + (size_t)M_ * 64;
  unsigned short* dtf = (unsigned short*)(xdr + (size_t)M_ * 64);   // fp16 dt
  unsigned short* dtr = dtf + (size_t)M_ * DI_;
  // E/Hin fp16 (8.4 MB each); fp16 part2 (8.4 MB) aliases Eh, dead before passA
  unsigned short* Eh = dtr + (size_t)M_ * DI_;
  unsigned short* Hh = Eh + (size_t)2 * B_ * NC_ * DI_ * 16;
  float* dtsb = (float*)(Hh + (size_t)2 * B_ * NC_ * DI_ * 16);
  unsigned short* part2 = Eh;
  unsigned short* xzbf    = (unsigned short*)(dtsb + (size_t)2 * B_ * NC_ * DI_);
  unsigned short* xzbr    = xzbf + (size_t)M_ * 2048;
  unsigned short* xb      = xzbr + (size_t)M_ * 2048;
  unsigned short* Winb_f  = xb + (size_t)M_ * DM_;
  unsigned short* Winb_r  = Winb_f + (size_t)2048 * DM_;
  unsigned short* Woutb_f = Winb_r + (size_t)2048 * DM_;
  unsigned short* Woutb_r = Woutb_f + (size_t)DM_ * DI_;
  unsigned short* ybf     = Woutb_r + (size_t)DM_ * DI_;
  unsigned short* ybr     = ybf + (size_t)M_ * DI_;
  unsigned short* xsbf    = ybr + (size_t)M_ * DI_;
  unsigned short* xsbr    = xsbf + (size_t)M_ * DI_;
  unsigned short* Wxb_f   = xsbr + (size_t)M_ * DI_;
  unsigned short* Wxb_r   = Wxb_f + (size_t)64 * DI_;
  unsigned short* Wdtb_f  = Wxb_r + (size_t)64 * DI_;
  unsigned short* Wdtb_r  = Wdtb_f + (size_t)DI_ * DTR_;
  unsigned short* drbf    = Wdtb_r + (size_t)DI_ * DTR_;
  unsigned short* drbr    = drbf + (size_t)M_ * DTR_;
  float* Atabf = (float*)(drbr + (size_t)M_ * DTR_);     // [d][s] fp32
  float* Atabr = Atabf + (size_t)DI_ * DS_;

  dim3 blk(256);

  // cast x, Win_f/r, Wout_f/r, Wx_f/r, Wdt_f/r to bf16; precompute Atab
  {
    CastArgs ca;
    ca.src[0] = x;      ca.dst[0] = xb;      ca.n[0] = M_ * DM_;
    ca.src[1] = Win_f;  ca.dst[1] = Winb_f;  ca.n[1] = 2048 * DM_;
    ca.src[2] = Win_r;  ca.dst[2] = Winb_r;  ca.n[2] = 2048 * DM_;
    ca.src[3] = Wout_f; ca.dst[3] = Woutb_f; ca.n[3] = DM_ * DI_;
    ca.src[4] = Wout_r; ca.dst[4] = Woutb_r; ca.n[4] = DM_ * DI_;
    ca.src[5] = Wx_f;   ca.dst[5] = Wxb_f;   ca.n[5] = 64 * DI_;
    ca.src[6] = Wx_r;   ca.dst[6] = Wxb_r;   ca.n[6] = 64 * DI_;
    ca.src[7] = Wdt_f;  ca.dst[7] = Wdtb_f;  ca.n[7] = DI_ * DTR_;
    ca.src[8] = Wdt_r;  ca.dst[8] = Wdtb_r;  ca.n[8] = DI_ * DTR_;
    int st = 0;
    for (int s = 0; s < 9; ++s) { ca.start[s] = st; st += ca.n[s]; }
    int total4 = st / 4;
    cast_multi_k<<<(total4 + 255) / 256, blk, 0, stream>>>(
        ca, total4, Alog_f, Alog_r, Atabf, Atabr);
  }

  // GEMM1 (bf16 MFMA, dirs fused, 3-buf counted-vmcnt pipeline)
  gemm1_mfma_k<<<dim3(2048 / 128, M_ / 128), blk, 0, stream>>>(
      xb, Winb_f, Winb_r, xzbf, xzbr);

  // conv + silu (both dirs, 8 timesteps/block), bf16 in/out
  conv_silu_k<<<2 * B_ * (L_ / 8), blk, 0, stream>>>(xzbf, xzbr, convw_f, convb_f,
      convw_r, convb_r, xsbf, xsbr);

  // GEMM2 (bf16 MFMA split-K, both dirs, fp16 partials) + reduce
  gemm2_mfma_k<<<dim3(KS_, M_ / 128, 2), blk, 0, stream>>>(
      xsbf, xsbr, Wxb_f, Wxb_r, part2);
  reduce_part_k<<<(2 * M_ * 16) / 256, blk, 0, stream>>>(part2, xdf, xdr,
      drbf, drbr);

  // GEMM3 (bf16 MFMA, both dirs): dt = softplus(dt_raw . Wdt^T + dtb) -> fp16
  gemm3_mfma_k<<<dim3(DI_ / 128, M_ / 128, 2), blk, 0, stream>>>(
      drbf, drbr, Wdtb_f, Wdtb_r, dtb_f, dtb_r, dtf, dtr);

  // chunked scan (A -> prefix -> C), P recomputed from dtsum
  scan_passA_k<<<2 * B_ * NC_ * 4, blk, 0, stream>>>(dtf, dtr, xsbf, xsbr,
      xdf, xdr, Atabf, Atabr, Eh, dtsb);
  scan_prefix_k<<<(2 * B_ * DI_ * 16) / 256, blk, 0, stream>>>(
      Eh, dtsb, Atabf, Atabr, Hh);
  scan_passC_k<<<2 * B_ * NC_ * 4, blk, 0, stream>>>(dtf, dtr, xsbf, xsbr,
      xdf, xdr, xzbf, xzbr, Atabf, Atabr, Dp_f, Dp_r, Hh, ybf, ybr);

  // GEMM4 fused (both dirs + add, 3-buf counted-vmcnt pipeline)
  gemm4_fused_k<<<dim3(DM_ / 64, M_ / 128), dim3(512), 0, stream>>>(
      ybf, Woutb_f, ybr, Woutb_r, out);
}